// Round 1
// baseline (146.684 us; speedup 1.0000x reference)
//
#include <hip/hip_runtime.h>
#include <cstdint>

#define DEVINL __device__ __forceinline__

typedef __attribute__((ext_vector_type(8))) short bf16x8;
typedef __attribute__((ext_vector_type(4))) float f32x4;
typedef __attribute__((ext_vector_type(8))) unsigned short u16x8;

#define MFMA16(a, b, c) __builtin_amdgcn_mfma_f32_16x16x32_bf16(a, b, c, 0, 0, 0)

DEVINL unsigned short f2bf(float x) {
  unsigned int u = __builtin_bit_cast(unsigned int, x);
  u += 0x7FFFu + ((u >> 16) & 1u);
  return (unsigned short)(u >> 16);
}
DEVINL float bf2f(unsigned short s) {
  unsigned int u = ((unsigned int)s) << 16;
  return __builtin_bit_cast(float, u);
}
DEVINL void gload_lds16(const void* g, void* l) {
  __builtin_amdgcn_global_load_lds(
      (const __attribute__((address_space(1))) unsigned int*)g,
      (__attribute__((address_space(3))) unsigned int*)l, 16, 0, 0);
}

// ---------------- f32 -> bf16 convert (vectorized) ----------------
__global__ __launch_bounds__(256) void k_convert(const float* __restrict__ src,
                                                 unsigned short* __restrict__ dst,
                                                 int n8) {
  int idx = blockIdx.x * blockDim.x + threadIdx.x;
  int stride = gridDim.x * blockDim.x;
  const float4* s4 = (const float4*)src;
  for (int i = idx; i < n8; i += stride) {
    float4 a = s4[2 * i], b = s4[2 * i + 1];
    u16x8 o;
    o[0] = f2bf(a.x); o[1] = f2bf(a.y); o[2] = f2bf(a.z); o[3] = f2bf(a.w);
    o[4] = f2bf(b.x); o[5] = f2bf(b.y); o[6] = f2bf(b.z); o[7] = f2bf(b.w);
    *(u16x8*)(dst + 8 * i) = o;
  }
}

// ---------------- per-(b,h,q) gate term: f(q) = 5*sigmoid(5(e-0.3)) - 0.3e ---
__global__ void k_fq(const float* __restrict__ ent, float* __restrict__ fq, int n) {
  int i = blockIdx.x * 256 + threadIdx.x;
  if (i < n) {
    float e = ent[i];
    float Et = 1.f / (1.f + __expf(-5.f * (e - 0.3f)));
    fq[i] = 5.f * Et - 0.3f * e;
  }
}

// ---------------- per-(b,h,k) gate term: g(k) = 1.4*min(sum K^2/64, 2) -------
__global__ void k_gk(const unsigned short* __restrict__ K, float* __restrict__ gk, int n) {
  int i = blockIdx.x * 256 + threadIdx.x;
  if (i >= n) return;
  const bf16x8* p = (const bf16x8*)(K + (size_t)i * 64);
  float s = 0.f;
  for (int c = 0; c < 8; ++c) {
    bf16x8 v = p[c];
    for (int j = 0; j < 8; ++j) {
      float f = bf2f((unsigned short)v[j]);
      s += f * f;
    }
  }
  gk[i] = 1.4f * fminf(s * (1.f / 64.f), 2.f);
}

// ---------------- V (b,h,s,d) -> Vt (b,h,d,s) transpose ----------------------
__global__ __launch_bounds__(256) void k_transpose(const unsigned short* __restrict__ V,
                                                   unsigned short* __restrict__ Vt) {
  __shared__ __align__(16) unsigned short tile[64][80];  // pad: 160B rows, 16B-aligned
  const int bh = blockIdx.y, s0 = blockIdx.x * 64;
  const int t = threadIdx.x;
  for (int i = 0; i < 2; ++i) {
    int row = (t >> 3) + 32 * i, c = t & 7;
    *(uint4*)&tile[row][c * 8] =
        *(const uint4*)(V + ((size_t)bh * 1024 + s0 + row) * 64 + c * 8);
  }
  __syncthreads();
  for (int i = 0; i < 2; ++i) {
    int d = (t >> 3) + 32 * i, sc = t & 7;
    u16x8 o;
    for (int u = 0; u < 8; ++u) o[u] = tile[sc * 8 + u][d];
    *(u16x8*)(Vt + ((size_t)bh * 64 + d) * 1024 + s0 + sc * 8) = o;
  }
}

// ---------------- 128x128-tile bf16 GEMM, C = A * B^T ------------------------
// MODE 0: scatter-store bf16 into Q/K/V (B,H,S,64).  MODE 1: f32 store to Cout.
template <int MODE>
__global__ __launch_bounds__(256) void k_gemm(const unsigned short* __restrict__ A,
                                              const unsigned short* __restrict__ Bw,
                                              int Kdim, unsigned short* Qo,
                                              unsigned short* Ko, unsigned short* Vo,
                                              float* Cout, int Ncols) {
  __shared__ __align__(16) unsigned short As[128 * 32];
  __shared__ __align__(16) unsigned short Bs[128 * 32];
  const int t = threadIdx.x;
  const int m0 = blockIdx.y * 128, n0 = blockIdx.x * 128;
  const int lane = t & 63, w = t >> 6;
  const int wr = w >> 1, wc = w & 1, lm = lane & 15, lg = lane >> 4;
  const int rowA = t >> 2, cch = t & 3;
  f32x4 acc[4][4] = {};
  for (int kt = 0; kt < Kdim; kt += 32) {
    for (int i = 0; i < 2; ++i) {
      gload_lds16(A + (size_t)(m0 + rowA + 64 * i) * Kdim + kt + cch * 8,
                  (char*)As + t * 16 + i * 4096);
      gload_lds16(Bw + (size_t)(n0 + rowA + 64 * i) * Kdim + kt + cch * 8,
                  (char*)Bs + t * 16 + i * 4096);
    }
    __syncthreads();
    bf16x8 af[4], bfr[4];
    for (int mt = 0; mt < 4; ++mt)
      af[mt] = *(const bf16x8*)(As + (wr * 64 + mt * 16 + lm) * 32 + lg * 8);
    for (int nt = 0; nt < 4; ++nt)
      bfr[nt] = *(const bf16x8*)(Bs + (wc * 64 + nt * 16 + lm) * 32 + lg * 8);
    for (int mt = 0; mt < 4; ++mt)
      for (int nt = 0; nt < 4; ++nt)
        acc[mt][nt] = MFMA16(af[mt], bfr[nt], acc[mt][nt]);
    __syncthreads();
  }
  for (int mt = 0; mt < 4; ++mt)
    for (int nt = 0; nt < 4; ++nt)
      for (int r = 0; r < 4; ++r) {
        int m = m0 + wr * 64 + mt * 16 + lg * 4 + r;
        int n = n0 + wc * 64 + nt * 16 + lm;
        float v = acc[mt][nt][r];
        if (MODE == 0) {
          int which = n >> 10, e = n & 1023, h = e >> 6, d = e & 63;
          int b = m >> 10, s = m & 1023;
          unsigned short* dst = which == 0 ? Qo : (which == 1 ? Ko : Vo);
          dst[(size_t)(((b << 4) + h) * 1024 + s) * 64 + d] = f2bf(v);
        } else {
          Cout[(size_t)m * Ncols + n] = v;
        }
      }
}

// ---------------- fused gated flash attention + entropy ----------------------
// grid (S/128, B*H); 4 waves/block, 32 q-rows per wave, KBLK = 64.
__global__ __launch_bounds__(256) void k_attn(const unsigned short* __restrict__ Q,
                                              const unsigned short* __restrict__ Kt,
                                              const unsigned short* __restrict__ Vt,
                                              const float* __restrict__ fq,
                                              const float* __restrict__ gk,
                                              unsigned short* __restrict__ Ob,
                                              float* __restrict__ Sst) {
  __shared__ __align__(16) unsigned short Ks[64 * 64];    // [k][d], XOR-swizzled
  __shared__ __align__(16) unsigned short Vs[64 * 64];    // [d][k], XOR-swizzled
  __shared__ __align__(16) unsigned short Ps[4][32 * 64]; // per-wave P, swizzled
  __shared__ float gks[64];
  const int bh = blockIdx.y, q0 = blockIdx.x * 128;
  const int t = threadIdx.x, lane = t & 63, w = t >> 6;
  const int lm = lane & 15, lg = lane >> 4;
  const int b = bh >> 4, h = bh & 15;
  const size_t bhS = (size_t)bh * 1024;
  const int qbase = q0 + w * 32;

  bf16x8 qf[2][2];
  float fqr[2][4];
  for (int mt = 0; mt < 2; ++mt) {
    for (int ks = 0; ks < 2; ++ks)
      qf[mt][ks] = *(const bf16x8*)(Q + (bhS + qbase + mt * 16 + lm) * 64 + ks * 32 + lg * 8);
    for (int r = 0; r < 4; ++r)
      fqr[mt][r] = fq[bhS + qbase + mt * 16 + lg * 4 + r];
  }
  f32x4 Oacc[2][4] = {};
  float m_r[2][4], l_r[2][4], W_r[2][4];
  for (int mt = 0; mt < 2; ++mt)
    for (int r = 0; r < 4; ++r) { m_r[mt][r] = -1e30f; l_r[mt][r] = 0.f; W_r[mt][r] = 0.f; }

  for (int kt = 0; kt < 16; ++kt) {
    const int k0 = kt * 64;
    {  // stage K,Vt tiles via global_load_lds, pre-swizzled source (T2/m173)
      int row = t >> 3, c = t & 7;
      for (int i = 0; i < 2; ++i) {
        int rr = row + 32 * i;
        gload_lds16(Kt + (bhS + k0 + rr) * 64 + ((c ^ (rr & 7)) * 8),
                    (char*)Ks + t * 16 + i * 4096);
        gload_lds16(Vt + ((size_t)bh * 64 + rr) * 1024 + k0 + ((c ^ (rr & 7)) * 8),
                    (char*)Vs + t * 16 + i * 4096);
      }
      if (t < 64) gks[t] = gk[bhS + k0 + t];
    }
    __syncthreads();

    // QK^T
    f32x4 c_[2][4] = {};
    for (int nt = 0; nt < 4; ++nt) {
      bf16x8 kb[2];
      for (int ks = 0; ks < 2; ++ks) {
        int row = nt * 16 + lm;
        int byo = ((ks * 32 + lg * 8) * 2) ^ ((row & 7) << 4);
        kb[ks] = *(const bf16x8*)((const char*)Ks + row * 128 + byo);
      }
      for (int mt = 0; mt < 2; ++mt)
        for (int ks = 0; ks < 2; ++ks)
          c_[mt][nt] = MFMA16(qf[mt][ks], kb[ks], c_[mt][nt]);
    }

    // gating + online softmax/entropy update
    float gkc[4];
    for (int nt = 0; nt < 4; ++nt) gkc[nt] = gks[nt * 16 + lm];
    for (int mt = 0; mt < 2; ++mt) {
      float g_[4][4], lmax[4] = {-3e38f, -3e38f, -3e38f, -3e38f};
      for (int nt = 0; nt < 4; ++nt)
        for (int r = 0; r < 4; ++r) {
          float s = c_[mt][nt][r] * 0.125f;
          float gl = fqr[mt][r] + gkc[nt];
          float v = s - __logf(1.f + __expf(-gl));  // s + log(sigmoid(gl))
          g_[nt][r] = v;
          lmax[r] = fmaxf(lmax[r], v);
        }
      for (int d = 1; d < 16; d <<= 1)
        for (int r = 0; r < 4; ++r) lmax[r] = fmaxf(lmax[r], __shfl_xor(lmax[r], d));
      float sc[4];
      for (int r = 0; r < 4; ++r) {
        float mn = fmaxf(m_r[mt][r], lmax[r]);
        float delta = m_r[mt][r] - mn;
        float s = __expf(delta);
        W_r[mt][r] = s * W_r[mt][r] + (s * delta) * l_r[mt][r];
        l_r[mt][r] *= s;
        m_r[mt][r] = mn;
        sc[r] = s;
      }
      for (int dt = 0; dt < 4; ++dt)
        for (int r = 0; r < 4; ++r) Oacc[mt][dt][r] *= sc[r];
      float psum[4] = {0, 0, 0, 0}, wsum[4] = {0, 0, 0, 0};
      for (int nt = 0; nt < 4; ++nt)
        for (int r = 0; r < 4; ++r) {
          float sh = g_[nt][r] - m_r[mt][r];
          float p = __expf(sh);
          psum[r] += p;
          wsum[r] += p * sh;
          int qrow = mt * 16 + lg * 4 + r;
          int byo = ((nt * 16 + lm) * 2) ^ ((qrow & 7) << 4);
          *(unsigned short*)((char*)Ps[w] + qrow * 128 + byo) = f2bf(p);
        }
      for (int d = 1; d < 16; d <<= 1)
        for (int r = 0; r < 4; ++r) {
          psum[r] += __shfl_xor(psum[r], d);
          wsum[r] += __shfl_xor(wsum[r], d);
        }
      for (int r = 0; r < 4; ++r) {
        l_r[mt][r] += psum[r];
        W_r[mt][r] += wsum[r];
      }
    }

    // PV (P via per-wave LDS buffer; same-wave ds ordering guarantees visibility)
    bf16x8 pa[2][2];
    for (int mt = 0; mt < 2; ++mt)
      for (int ks = 0; ks < 2; ++ks) {
        int qrow = mt * 16 + lm;
        int byo = ((ks * 32 + lg * 8) * 2) ^ ((qrow & 7) << 4);
        pa[mt][ks] = *(const bf16x8*)((const char*)Ps[w] + qrow * 128 + byo);
      }
    for (int dt = 0; dt < 4; ++dt) {
      bf16x8 vb[2];
      for (int ks = 0; ks < 2; ++ks) {
        int row = dt * 16 + lm;
        int byo = ((ks * 32 + lg * 8) * 2) ^ ((row & 7) << 4);
        vb[ks] = *(const bf16x8*)((const char*)Vs + row * 128 + byo);
      }
      for (int mt = 0; mt < 2; ++mt)
        for (int ks = 0; ks < 2; ++ks)
          Oacc[mt][dt] = MFMA16(pa[mt][ks], vb[ks], Oacc[mt][dt]);
    }
    __syncthreads();
  }

  // epilogue: normalize O, write bf16 O and f32 entropy
  for (int mt = 0; mt < 2; ++mt) {
    float inv[4], entv[4];
    for (int r = 0; r < 4; ++r) {
      float l = l_r[mt][r];
      inv[r] = 1.f / l;
      entv[r] = __logf(l) - W_r[mt][r] * inv[r];
    }
    for (int dt = 0; dt < 4; ++dt)
      for (int r = 0; r < 4; ++r) {
        int srow = qbase + mt * 16 + lg * 4 + r;
        int col = h * 64 + dt * 16 + lm;
        Ob[(size_t)(b * 1024 + srow) * 1024 + col] = f2bf(Oacc[mt][dt][r] * inv[r]);
      }
    if (lm == 0)
      for (int r = 0; r < 4; ++r) {
        int srow = qbase + mt * 16 + lg * 4 + r;
        Sst[bhS + srow] = entv[r];
      }
  }
}

// ---------------- workspace layout (bytes) ----------------
static constexpr size_t OFF_XB = 0;                    // 4 MB  x bf16 [2048][1024]
static constexpr size_t OFF_WB = 4ull << 20;           // 6 MB  Wq|Wk|Wv bf16 [3072][1024]
static constexpr size_t OFF_Q = 10ull << 20;           // 4 MB  Q bf16 (B,H,S,64)
static constexpr size_t OFF_K = 14ull << 20;           // 4 MB  K bf16
static constexpr size_t OFF_V = 18ull << 20;           // 4 MB  V bf16 (later reused as Ob)
static constexpr size_t OFF_VT = 22ull << 20;          // 4 MB  V^T bf16 (B,H,64,S)
static constexpr size_t OFF_WOB = 26ull << 20;         // 2 MB  Wo bf16
static constexpr size_t OFF_FQ = 28ull << 20;          // 128 KB f32
static constexpr size_t OFF_GK = (28ull << 20) + (128ull << 10);  // 128 KB f32

extern "C" void kernel_launch(void* const* d_in, const int* in_sizes, int n_in,
                              void* d_out, int out_size, void* d_ws, size_t ws_size,
                              hipStream_t stream) {
  const float* x = (const float*)d_in[0];
  const float* ent = (const float*)d_in[1];
  const float* Wq = (const float*)d_in[2];
  const float* Wk = (const float*)d_in[3];
  const float* Wv = (const float*)d_in[4];
  const float* Wo = (const float*)d_in[5];
  (void)in_sizes; (void)n_in; (void)out_size; (void)ws_size;

  char* ws = (char*)d_ws;
  unsigned short* xb = (unsigned short*)(ws + OFF_XB);
  unsigned short* Wb = (unsigned short*)(ws + OFF_WB);
  unsigned short* Qb = (unsigned short*)(ws + OFF_Q);
  unsigned short* Kb = (unsigned short*)(ws + OFF_K);
  unsigned short* Vb = (unsigned short*)(ws + OFF_V);
  unsigned short* Vtb = (unsigned short*)(ws + OFF_VT);
  unsigned short* Ob = (unsigned short*)(ws + OFF_V);  // alias: V dead after transpose
  unsigned short* Wob = (unsigned short*)(ws + OFF_WOB);
  float* fqd = (float*)(ws + OFF_FQ);
  float* gkd = (float*)(ws + OFF_GK);
  float* outp = (float*)d_out;
  float* Sst = outp + 2u * 1024u * 1024u;

  k_convert<<<1024, 256, 0, stream>>>(x, xb, 2097152 / 8);
  k_convert<<<512, 256, 0, stream>>>(Wq, Wb, 1048576 / 8);
  k_convert<<<512, 256, 0, stream>>>(Wk, Wb + 1048576, 1048576 / 8);
  k_convert<<<512, 256, 0, stream>>>(Wv, Wb + 2097152, 1048576 / 8);
  k_convert<<<512, 256, 0, stream>>>(Wo, Wob, 1048576 / 8);
  k_fq<<<128, 256, 0, stream>>>(ent, fqd, 32768);

  k_gemm<0><<<dim3(24, 16), 256, 0, stream>>>(xb, Wb, 1024, Qb, Kb, Vb, nullptr, 0);

  k_gk<<<128, 256, 0, stream>>>(Kb, gkd, 32768);
  k_transpose<<<dim3(16, 32), 256, 0, stream>>>(Vb, Vtb);

  k_attn<<<dim3(8, 32), 256, 0, stream>>>(Qb, Kb, Vtb, fqd, gkd, Ob, Sst);

  k_gemm<1><<<dim3(8, 16), 256, 0, stream>>>(Ob, Wob, 1024, nullptr, nullptr, nullptr,
                                             outp, 1024);
}

// Round 2
// 102.290 us; speedup vs baseline: 1.4340x; 1.4340x over previous
//
#include <hip/hip_runtime.h>
#include <cstdint>

#define DEVINL __device__ __forceinline__

typedef __attribute__((ext_vector_type(8))) short bf16x8;
typedef __attribute__((ext_vector_type(4))) float f32x4;
typedef __attribute__((ext_vector_type(8))) unsigned short u16x8;

#define MFMA16(a, b, c) __builtin_amdgcn_mfma_f32_16x16x32_bf16(a, b, c, 0, 0, 0)

DEVINL unsigned short f2bf(float x) {
  unsigned int u = __builtin_bit_cast(unsigned int, x);
  u += 0x7FFFu + ((u >> 16) & 1u);
  return (unsigned short)(u >> 16);
}
DEVINL float bf2f(unsigned short s) {
  unsigned int u = ((unsigned int)s) << 16;
  return __builtin_bit_cast(float, u);
}
DEVINL void gload_lds16(const void* g, void* l) {
  __builtin_amdgcn_global_load_lds(
      (const __attribute__((address_space(1))) unsigned int*)g,
      (__attribute__((address_space(3))) unsigned int*)l, 16, 0, 0);
}

// ---------------- fused prologue: f32->bf16 converts + efq ------------------
// blocks [0,1024): x  [1024,1536): Wq  [1536,2048): Wk  [2048,2560): Wv
// [2560,3072): Wo  [3072,3200): efq = exp(-(5*sigmoid(5(e-0.3)) - 0.3e))
__global__ __launch_bounds__(256) void k_prep(const float* __restrict__ x,
                                              const float* __restrict__ Wq,
                                              const float* __restrict__ Wk,
                                              const float* __restrict__ Wv,
                                              const float* __restrict__ Wo,
                                              const float* __restrict__ ent,
                                              unsigned short* __restrict__ xb,
                                              unsigned short* __restrict__ Wb,
                                              unsigned short* __restrict__ Wob,
                                              float* __restrict__ efq) {
  const int bid = blockIdx.x;
  if (bid < 3072) {
    const float* src;
    unsigned short* dst;
    int base;
    if (bid < 1024)      { src = x;  dst = xb;            base = bid; }
    else if (bid < 1536) { src = Wq; dst = Wb;            base = bid - 1024; }
    else if (bid < 2048) { src = Wk; dst = Wb + (1u<<20); base = bid - 1536; }
    else if (bid < 2560) { src = Wv; dst = Wb + (2u<<20); base = bid - 2048; }
    else                 { src = Wo; dst = Wob;           base = bid - 2560; }
    int i = base * 256 + threadIdx.x;
    const float4* s4 = (const float4*)src;
    float4 a = s4[2 * i], b = s4[2 * i + 1];
    u16x8 o;
    o[0] = f2bf(a.x); o[1] = f2bf(a.y); o[2] = f2bf(a.z); o[3] = f2bf(a.w);
    o[4] = f2bf(b.x); o[5] = f2bf(b.y); o[6] = f2bf(b.z); o[7] = f2bf(b.w);
    *(u16x8*)(dst + 8 * i) = o;
  } else {
    int i = (bid - 3072) * 256 + threadIdx.x;  // 32768 total
    float e = ent[i];
    float Et = 1.f / (1.f + __expf(-5.f * (e - 0.3f)));
    efq[i] = __expf(-(5.f * Et - 0.3f * e));
  }
}

// ---------------- per-(b,h,k): egk = exp(-1.4*min(sum K^2/64, 2)) -----------
__global__ void k_gk(const unsigned short* __restrict__ K, float* __restrict__ egk,
                     int n) {
  int i = blockIdx.x * 256 + threadIdx.x;
  if (i >= n) return;
  const bf16x8* p = (const bf16x8*)(K + (size_t)i * 64);
  float s = 0.f;
  for (int c = 0; c < 8; ++c) {
    bf16x8 v = p[c];
    for (int j = 0; j < 8; ++j) {
      float f = bf2f((unsigned short)v[j]);
      s += f * f;
    }
  }
  float g = 1.4f * fminf(s * (1.f / 64.f), 2.f);
  egk[i] = __expf(-g);
}

// ---------------- V (b,h,s,d) -> Vt (b,h,d,s) transpose ----------------------
__global__ __launch_bounds__(256) void k_transpose(const unsigned short* __restrict__ V,
                                                   unsigned short* __restrict__ Vt) {
  __shared__ __align__(16) unsigned short tile[64][80];
  const int bh = blockIdx.y, s0 = blockIdx.x * 64;
  const int t = threadIdx.x;
  for (int i = 0; i < 2; ++i) {
    int row = (t >> 3) + 32 * i, c = t & 7;
    *(uint4*)&tile[row][c * 8] =
        *(const uint4*)(V + ((size_t)bh * 1024 + s0 + row) * 64 + c * 8);
  }
  __syncthreads();
  for (int i = 0; i < 2; ++i) {
    int d = (t >> 3) + 32 * i, sc = t & 7;
    u16x8 o;
    for (int u = 0; u < 8; ++u) o[u] = tile[sc * 8 + u][d];
    *(u16x8*)(Vt + ((size_t)bh * 64 + d) * 1024 + s0 + sc * 8) = o;
  }
}

// ---------------- 128x128-tile bf16 GEMM, C = A * B^T ------------------------
// MODE 0: scatter-store bf16 into Q/K/V (B,H,S,64), Q scaled by 0.125.
// MODE 1: f32 store to Cout.
template <int MODE>
__global__ __launch_bounds__(256) void k_gemm(const unsigned short* __restrict__ A,
                                              const unsigned short* __restrict__ Bw,
                                              int Kdim, unsigned short* Qo,
                                              unsigned short* Ko, unsigned short* Vo,
                                              float* Cout, int Ncols) {
  __shared__ __align__(16) unsigned short As[128 * 32];
  __shared__ __align__(16) unsigned short Bs[128 * 32];
  const int t = threadIdx.x;
  const int m0 = blockIdx.y * 128, n0 = blockIdx.x * 128;
  const int lane = t & 63, w = t >> 6;
  const int wr = w >> 1, wc = w & 1, lm = lane & 15, lg = lane >> 4;
  const int rowA = t >> 2, cch = t & 3;
  f32x4 acc[4][4] = {};
  for (int kt = 0; kt < Kdim; kt += 32) {
    for (int i = 0; i < 2; ++i) {
      gload_lds16(A + (size_t)(m0 + rowA + 64 * i) * Kdim + kt + cch * 8,
                  (char*)As + t * 16 + i * 4096);
      gload_lds16(Bw + (size_t)(n0 + rowA + 64 * i) * Kdim + kt + cch * 8,
                  (char*)Bs + t * 16 + i * 4096);
    }
    __syncthreads();
    bf16x8 af[4], bfr[4];
    for (int mt = 0; mt < 4; ++mt)
      af[mt] = *(const bf16x8*)(As + (wr * 64 + mt * 16 + lm) * 32 + lg * 8);
    for (int nt = 0; nt < 4; ++nt)
      bfr[nt] = *(const bf16x8*)(Bs + (wc * 64 + nt * 16 + lm) * 32 + lg * 8);
    for (int mt = 0; mt < 4; ++mt)
      for (int nt = 0; nt < 4; ++nt)
        acc[mt][nt] = MFMA16(af[mt], bfr[nt], acc[mt][nt]);
    __syncthreads();
  }
  const float scl = (MODE == 0 && n0 < 1024) ? 0.125f : 1.f;  // fold 1/sqrt(Dh) into Q
  for (int mt = 0; mt < 4; ++mt)
    for (int nt = 0; nt < 4; ++nt)
      for (int r = 0; r < 4; ++r) {
        int m = m0 + wr * 64 + mt * 16 + lg * 4 + r;
        int n = n0 + wc * 64 + nt * 16 + lm;
        float v = acc[mt][nt][r];
        if (MODE == 0) {
          v *= scl;
          int which = n >> 10, e = n & 1023, h = e >> 6, d = e & 63;
          int b = m >> 10, s = m & 1023;
          unsigned short* dst = which == 0 ? Qo : (which == 1 ? Ko : Vo);
          dst[(size_t)(((b << 4) + h) * 1024 + s) * 64 + d] = f2bf(v);
        } else {
          Cout[(size_t)m * Ncols + n] = v;
        }
      }
}

// ---------------- fused gated flash attention + entropy ----------------------
// grid (S/64, B*H); 4 waves/block, 16 q-rows per wave, KBLK = 64.
// Swapped QK^T: mfma(K, Q) -> lane owns q = lane&15; k = nt*16 + lg*4 + r.
__global__ __launch_bounds__(256) void k_attn(const unsigned short* __restrict__ Q,
                                              const unsigned short* __restrict__ Kt,
                                              const unsigned short* __restrict__ Vt,
                                              const float* __restrict__ efq,
                                              const float* __restrict__ egk,
                                              unsigned short* __restrict__ Ob,
                                              float* __restrict__ Sst) {
  __shared__ __align__(16) unsigned short Ks[64 * 64];  // [k][d] swizzled
  __shared__ __align__(16) unsigned short Vs[64 * 64];  // [d][k] swizzled
  __shared__ __align__(16) unsigned int Ps[4][16][32];  // per-wave P (u32 pairs), swizzled
  __shared__ __align__(16) float egks[64];
  const int bh = blockIdx.y, q0 = blockIdx.x * 64;
  const int t = threadIdx.x, lane = t & 63, w = t >> 6;
  const int lm = lane & 15, lg = lane >> 4;
  const int b = bh >> 4, h = bh & 15;
  const size_t bhS = (size_t)bh << 10;
  const int qb = q0 + w * 16;

  bf16x8 qf[2];
#pragma unroll
  for (int ks = 0; ks < 2; ++ks)
    qf[ks] = *(const bf16x8*)(Q + (bhS + qb + lm) * 64 + ks * 32 + lg * 8);
  const float efql = efq[bhS + qb + lm];

  f32x4 Oacc[4] = {};
  float m_r = -1e30f, l_r = 0.f, W_r = 0.f;

  for (int kt = 0; kt < 16; ++kt) {
    const int k0 = kt * 64;
    {  // stage K,Vt via global_load_lds with pre-swizzled source (T2/m173)
      int row = t >> 3, c = t & 7;
#pragma unroll
      for (int i = 0; i < 2; ++i) {
        int rr = row + 32 * i;
        gload_lds16(Kt + (bhS + k0 + rr) * 64 + ((c ^ (rr & 7)) * 8),
                    (char*)Ks + t * 16 + i * 4096);
        gload_lds16(Vt + ((size_t)bh * 64 + rr) * 1024 + k0 + ((c ^ (rr & 7)) * 8),
                    (char*)Vs + t * 16 + i * 4096);
      }
      if (t < 64) egks[t] = egk[bhS + k0 + t];
    }
    __syncthreads();

    // swapped QK^T: c_[nt] holds S[q=lm][k = k0 + nt*16 + lg*4 + r]
    f32x4 c_[4];
#pragma unroll
    for (int nt = 0; nt < 4; ++nt) {
      c_[nt] = (f32x4){0.f, 0.f, 0.f, 0.f};
#pragma unroll
      for (int ks = 0; ks < 2; ++ks) {
        int row = nt * 16 + lm;
        int byo = ((ks * 32 + lg * 8) * 2) ^ ((row & 7) << 4);
        bf16x8 kb = *(const bf16x8*)((const char*)Ks + row * 128 + byo);
        c_[nt] = MFMA16(kb, qf[ks], c_[nt]);
      }
    }

    // gate: v = s + logsig(fq+gk); logsig = -log1p(efq*egk), poly (x<=0.402)
    float v_[4][4];
    float lmax = -3e38f;
#pragma unroll
    for (int nt = 0; nt < 4; ++nt) {
      f32x4 eg = *(const f32x4*)&egks[nt * 16 + lg * 4];
#pragma unroll
      for (int r = 0; r < 4; ++r) {
        float xg = efql * eg[r];
        float lsig = -xg * (1.f - xg * (0.5f - xg * (0.333333333f - xg * (0.25f - 0.2f * xg))));
        float vv = c_[nt][r] + lsig;
        v_[nt][r] = vv;
        lmax = fmaxf(lmax, vv);
      }
    }
    lmax = fmaxf(lmax, __shfl_xor(lmax, 16));
    lmax = fmaxf(lmax, __shfl_xor(lmax, 32));

    // defer-max (T13): entropy is shift-invariant, rescale only when needed
    if (__any(lmax > m_r + 5.f)) {
      float mn = fmaxf(m_r, lmax);
      float dd = m_r - mn;
      float sc = __expf(dd);
      W_r = sc * (W_r + dd * l_r);
      l_r *= sc;
      m_r = mn;
      float scO[4];
#pragma unroll
      for (int r = 0; r < 4; ++r)
        scO[r] = __shfl(sc, (lane & 48) | (lg * 4 + r));
#pragma unroll
      for (int dt = 0; dt < 4; ++dt)
#pragma unroll
        for (int r = 0; r < 4; ++r) Oacc[dt][r] *= scO[r];
    }

    // p = exp(v-m); accumulate l, W; pack p to bf16 pairs
    float psum = 0.f, wsum = 0.f;
    unsigned int pw[8];
#pragma unroll
    for (int nt = 0; nt < 4; ++nt) {
      float p_[4];
#pragma unroll
      for (int r = 0; r < 4; ++r) {
        float sh = v_[nt][r] - m_r;
        float p = __expf(sh);
        p_[r] = p;
        psum += p;
        wsum = fmaf(p, sh, wsum);
      }
      asm("v_cvt_pk_bf16_f32 %0, %1, %2" : "=v"(pw[nt * 2 + 0]) : "v"(p_[0]), "v"(p_[1]));
      asm("v_cvt_pk_bf16_f32 %0, %1, %2" : "=v"(pw[nt * 2 + 1]) : "v"(p_[2]), "v"(p_[3]));
    }
    psum += __shfl_xor(psum, 16);
    psum += __shfl_xor(psum, 32);
    wsum += __shfl_xor(wsum, 16);
    wsum += __shfl_xor(wsum, 32);
    l_r += psum;
    W_r += wsum;

    // P -> LDS (u32-pair writes, XOR-swizzled; same-wave buffer)
    unsigned int* prow = &Ps[w][lm][0];
    const int sw = (lm & 7) << 2;
#pragma unroll
    for (int nt = 0; nt < 4; ++nt) {
      int idx = (nt * 8 + lg * 2) ^ sw;
      uint2 pr;
      pr.x = pw[nt * 2 + 0];
      pr.y = pw[nt * 2 + 1];
      *(uint2*)(prow + idx) = pr;
    }

    // PV: A = P[q][k], B = V^T[d][k]
    bf16x8 pa[2];
#pragma unroll
    for (int ks = 0; ks < 2; ++ks) {
      int idx = (ks * 16 + lg * 4) ^ sw;
      pa[ks] = *(const bf16x8*)(prow + idx);
    }
#pragma unroll
    for (int dt = 0; dt < 4; ++dt) {
#pragma unroll
      for (int ks = 0; ks < 2; ++ks) {
        int row = dt * 16 + lm;
        int byo = ((ks * 32 + lg * 8) * 2) ^ ((row & 7) << 4);
        bf16x8 vb = *(const bf16x8*)((const char*)Vs + row * 128 + byo);
        Oacc[dt] = MFMA16(pa[ks], vb, Oacc[dt]);
      }
    }
    __syncthreads();
  }

  // epilogue
  float invl = 1.f / l_r;
  float entv = __logf(l_r) - W_r * invl;
  float invO[4];
#pragma unroll
  for (int r = 0; r < 4; ++r)
    invO[r] = __shfl(invl, (lane & 48) | (lg * 4 + r));
#pragma unroll
  for (int dt = 0; dt < 4; ++dt)
#pragma unroll
    for (int r = 0; r < 4; ++r) {
      int srow = qb + lg * 4 + r;
      int col = h * 64 + dt * 16 + lm;
      Ob[(size_t)(b * 1024 + srow) * 1024 + col] = f2bf(Oacc[dt][r] * invO[r]);
    }
  if (lg == 0) Sst[bhS + qb + lm] = entv;
}

// ---------------- workspace layout (bytes) ----------------
static constexpr size_t OFF_XB = 0;                    // 4 MB  x bf16
static constexpr size_t OFF_WB = 4ull << 20;           // 6 MB  Wq|Wk|Wv bf16
static constexpr size_t OFF_Q = 10ull << 20;           // 4 MB  Q bf16 (B,H,S,64), pre-scaled
static constexpr size_t OFF_K = 14ull << 20;           // 4 MB  K bf16
static constexpr size_t OFF_V = 18ull << 20;           // 4 MB  V bf16 (reused as Ob)
static constexpr size_t OFF_VT = 22ull << 20;          // 4 MB  V^T bf16 (B,H,64,S)
static constexpr size_t OFF_WOB = 26ull << 20;         // 2 MB  Wo bf16
static constexpr size_t OFF_FQ = 28ull << 20;          // 128 KB f32 exp(-fq)
static constexpr size_t OFF_GK = (28ull << 20) + (128ull << 10);  // 128 KB f32 exp(-gk)

extern "C" void kernel_launch(void* const* d_in, const int* in_sizes, int n_in,
                              void* d_out, int out_size, void* d_ws, size_t ws_size,
                              hipStream_t stream) {
  const float* x = (const float*)d_in[0];
  const float* ent = (const float*)d_in[1];
  const float* Wq = (const float*)d_in[2];
  const float* Wk = (const float*)d_in[3];
  const float* Wv = (const float*)d_in[4];
  const float* Wo = (const float*)d_in[5];
  (void)in_sizes; (void)n_in; (void)out_size; (void)ws_size;

  char* ws = (char*)d_ws;
  unsigned short* xb = (unsigned short*)(ws + OFF_XB);
  unsigned short* Wb = (unsigned short*)(ws + OFF_WB);
  unsigned short* Qb = (unsigned short*)(ws + OFF_Q);
  unsigned short* Kb = (unsigned short*)(ws + OFF_K);
  unsigned short* Vb = (unsigned short*)(ws + OFF_V);
  unsigned short* Vtb = (unsigned short*)(ws + OFF_VT);
  unsigned short* Ob = (unsigned short*)(ws + OFF_V);  // alias: V dead after transpose
  unsigned short* Wob = (unsigned short*)(ws + OFF_WOB);
  float* efqd = (float*)(ws + OFF_FQ);
  float* egkd = (float*)(ws + OFF_GK);
  float* outp = (float*)d_out;
  float* Sst = outp + 2u * 1024u * 1024u;

  k_prep<<<3200, 256, 0, stream>>>(x, Wq, Wk, Wv, Wo, ent, xb, Wb, Wob, efqd);

  k_gemm<0><<<dim3(24, 16), 256, 0, stream>>>(xb, Wb, 1024, Qb, Kb, Vb, nullptr, 0);

  k_gk<<<128, 256, 0, stream>>>(Kb, egkd, 32768);
  k_transpose<<<dim3(16, 32), 256, 0, stream>>>(Vb, Vtb);

  k_attn<<<dim3(16, 32), 256, 0, stream>>>(Qb, Kb, Vtb, efqd, egkd, Ob, Sst);

  k_gemm<1><<<dim3(8, 16), 256, 0, stream>>>(Ob, Wob, 1024, nullptr, nullptr, nullptr,
                                             outp, 1024);
}

// Round 3
// 78.833 us; speedup vs baseline: 1.8607x; 1.2976x over previous
//
#include <hip/hip_runtime.h>
#include <cstdint>

#define DEVINL __device__ __forceinline__

typedef __attribute__((ext_vector_type(8))) short bf16x8;
typedef __attribute__((ext_vector_type(4))) float f32x4;
typedef __attribute__((ext_vector_type(8))) unsigned short u16x8;
typedef unsigned short u16;
typedef unsigned int u32;

#define MFMA16(a, b, c) __builtin_amdgcn_mfma_f32_16x16x32_bf16(a, b, c, 0, 0, 0)

DEVINL u16 f2bf(float x) {
  u32 u = __builtin_bit_cast(u32, x);
  u += 0x7FFFu + ((u >> 16) & 1u);
  return (u16)(u >> 16);
}
DEVINL float bf2f(u16 s) {
  u32 u = ((u32)s) << 16;
  return __builtin_bit_cast(float, u);
}
DEVINL void gload_lds16(const void* g, void* l) {
  __builtin_amdgcn_global_load_lds(
      (const __attribute__((address_space(1))) unsigned int*)g,
      (__attribute__((address_space(3))) unsigned int*)l, 16, 0, 0);
}

// ---------------- fused prologue: f32->bf16 converts + efq ------------------
__global__ __launch_bounds__(256) void k_prep(const float* __restrict__ x,
                                              const float* __restrict__ Wq,
                                              const float* __restrict__ Wk,
                                              const float* __restrict__ Wv,
                                              const float* __restrict__ Wo,
                                              const float* __restrict__ ent,
                                              u16* __restrict__ xb,
                                              u16* __restrict__ Wb,
                                              u16* __restrict__ Wob,
                                              float* __restrict__ efq) {
  const int bid = blockIdx.x;
  if (bid < 3072) {
    const float* src;
    u16* dst;
    int base;
    if (bid < 1024)      { src = x;  dst = xb;            base = bid; }
    else if (bid < 1536) { src = Wq; dst = Wb;            base = bid - 1024; }
    else if (bid < 2048) { src = Wk; dst = Wb + (1u<<20); base = bid - 1536; }
    else if (bid < 2560) { src = Wv; dst = Wb + (2u<<20); base = bid - 2048; }
    else                 { src = Wo; dst = Wob;           base = bid - 2560; }
    int i = base * 256 + threadIdx.x;
    const float4* s4 = (const float4*)src;
    float4 a = s4[2 * i], b = s4[2 * i + 1];
    u16x8 o;
    o[0] = f2bf(a.x); o[1] = f2bf(a.y); o[2] = f2bf(a.z); o[3] = f2bf(a.w);
    o[4] = f2bf(b.x); o[5] = f2bf(b.y); o[6] = f2bf(b.z); o[7] = f2bf(b.w);
    *(u16x8*)(dst + 8 * i) = o;
  } else {
    int i = (bid - 3072) * 256 + threadIdx.x;
    float e = ent[i];
    float Et = 1.f / (1.f + __expf(-5.f * (e - 0.3f)));
    efq[i] = __expf(-(5.f * Et - 0.3f * e));
  }
}

// ---------------- tiled bf16 GEMM, C = A * B^T, BK=64, swizzled LDS ----------
// MODE 0 (BM=128,BN=128): QKV. Q scaled 0.125 -> Qo; K -> Ko + egk epilogue;
//   V -> transposed store into Vt (b,h,d,s) via LDS re-transpose.
// MODE 1 (BM=64,BN=128): f32 store to Cout (N=1024).
template <int BM, int BN, int MODE>
__global__ __launch_bounds__(256) void k_gemm(const u16* __restrict__ A,
                                              const u16* __restrict__ Bw,
                                              int Kdim, u16* __restrict__ Qo,
                                              u16* __restrict__ Ko,
                                              u16* __restrict__ Vt,
                                              float* __restrict__ egk_out,
                                              float* __restrict__ Cout) {
  constexpr int MT = BM / 32, NT = BN / 32;
  __shared__ __align__(16) u16 SM[(BM + BN) * 64];
  u16* As = SM;
  u16* Bs = SM + BM * 64;
  const int t = threadIdx.x;
  const int m0 = blockIdx.y * BM, n0 = blockIdx.x * BN;
  const int lane = t & 63, w = t >> 6;
  const int wr = w >> 1, wc = w & 1, lm = lane & 15, lg = lane >> 4;
  const int rs = t >> 3, cs = t & 7;
  f32x4 acc[MT][NT] = {};
  for (int kt = 0; kt < Kdim; kt += 64) {
#pragma unroll
    for (int i = 0; i < BM / 32; ++i) {
      int rr = rs + 32 * i;
      gload_lds16(A + (size_t)(m0 + rr) * Kdim + kt + ((cs ^ (rr & 7)) * 8),
                  (char*)As + t * 16 + i * 4096);
    }
#pragma unroll
    for (int i = 0; i < BN / 32; ++i) {
      int rr = rs + 32 * i;
      gload_lds16(Bw + (size_t)(n0 + rr) * Kdim + kt + ((cs ^ (rr & 7)) * 8),
                  (char*)Bs + t * 16 + i * 4096);
    }
    __syncthreads();
#pragma unroll
    for (int ks = 0; ks < 2; ++ks) {
      bf16x8 af[MT], bf[NT];
#pragma unroll
      for (int mt = 0; mt < MT; ++mt) {
        int row = wr * (BM / 2) + mt * 16 + lm;
        af[mt] = *(const bf16x8*)((const char*)As + row * 128 +
                                  (((ks * 4 + lg) ^ (row & 7)) << 4));
      }
#pragma unroll
      for (int nt = 0; nt < NT; ++nt) {
        int row = wc * (BN / 2) + nt * 16 + lm;
        bf[nt] = *(const bf16x8*)((const char*)Bs + row * 128 +
                                  (((ks * 4 + lg) ^ (row & 7)) << 4));
      }
#pragma unroll
      for (int mt = 0; mt < MT; ++mt)
#pragma unroll
        for (int nt = 0; nt < NT; ++nt)
          acc[mt][nt] = MFMA16(af[mt], bf[nt], acc[mt][nt]);
    }
    __syncthreads();
  }

  if (MODE == 1) {
#pragma unroll
    for (int mt = 0; mt < MT; ++mt)
#pragma unroll
      for (int nt = 0; nt < NT; ++nt)
#pragma unroll
        for (int r = 0; r < 4; ++r) {
          int m = m0 + wr * (BM / 2) + mt * 16 + lg * 4 + r;
          int n = n0 + wc * (BN / 2) + nt * 16 + lm;
          Cout[(size_t)m * 1024 + n] = acc[mt][nt][r];
        }
    return;
  }

  // MODE 0 epilogue: region by n0
  const int region = n0 >> 10;  // 0=Q 1=K 2=V
  const int b = m0 >> 10, s0 = m0 & 1023;
  if (region < 2) {
    u16* dst = region == 0 ? Qo : Ko;
    const float scl = region == 0 ? 0.125f : 1.f;
#pragma unroll
    for (int mt = 0; mt < MT; ++mt)
#pragma unroll
      for (int nt = 0; nt < NT; ++nt)
#pragma unroll
        for (int r = 0; r < 4; ++r) {
          int m = m0 + wr * 64 + mt * 16 + lg * 4 + r;
          int n = n0 + wc * 64 + nt * 16 + lm;
          int e = n & 1023, h = e >> 6, d = e & 63;
          dst[(size_t)(((b << 4) + h) * 1024 + (m & 1023)) * 64 + d] =
              f2bf(acc[mt][nt][r] * scl);
        }
    if (region == 1) {
      // egk = exp(-1.4*min(sum_d K^2/64, 2)); per wave covers one head (64 d)
      int hh = ((n0 - 1024) >> 6) + wc;
#pragma unroll
      for (int mt = 0; mt < MT; ++mt)
#pragma unroll
        for (int r = 0; r < 4; ++r) {
          float ss = 0.f;
#pragma unroll
          for (int nt = 0; nt < NT; ++nt) ss += acc[mt][nt][r] * acc[mt][nt][r];
          ss += __shfl_xor(ss, 1);
          ss += __shfl_xor(ss, 2);
          ss += __shfl_xor(ss, 4);
          ss += __shfl_xor(ss, 8);
          if (lm == 0) {
            int s = s0 + wr * 64 + mt * 16 + lg * 4 + r;
            float g = 1.4f * fminf(ss * (1.f / 64.f), 2.f);
            egk_out[(size_t)(((b << 4) + hh)) * 1024 + s] = __expf(-g);
          }
        }
    }
  } else {
    // V: transpose via LDS (one head per wave-column, two passes)
    u16* tile = SM;  // [64][128] u16, XOR-swizzled on m
#pragma unroll
    for (int half = 0; half < 2; ++half) {
      if (wc == half) {
#pragma unroll
        for (int mt = 0; mt < MT; ++mt)
#pragma unroll
          for (int nt = 0; nt < NT; ++nt)
#pragma unroll
            for (int r = 0; r < 4; ++r) {
              int d = nt * 16 + lm;
              int mloc = wr * 64 + mt * 16 + lg * 4 + r;
              tile[d * 128 + (mloc ^ ((d & 7) << 3))] = f2bf(acc[mt][nt][r]);
            }
      }
      __syncthreads();
      int hh = ((n0 - 2048) >> 6) + half;
#pragma unroll
      for (int j = 0; j < 4; ++j) {
        int dd = (t >> 4) + 16 * j, mc = t & 15;
        u16x8 v = *(const u16x8*)&tile[dd * 128 + ((mc * 8) ^ ((dd & 7) << 3))];
        *(u16x8*)(Vt + ((size_t)(((b << 4) + hh) * 64 + dd)) * 1024 + s0 + mc * 8) = v;
      }
      __syncthreads();
    }
  }
}

// ---------------- fused gated flash attention + entropy ----------------------
// grid 512 (XCD-swizzled); 4 waves/block, 16 q-rows/wave, KVBLK=128, dbuf LDS.
__global__ __launch_bounds__(256, 2) void k_attn(const u16* __restrict__ Q,
                                                 const u16* __restrict__ Kt,
                                                 const u16* __restrict__ Vt,
                                                 const float* __restrict__ efq,
                                                 const float* __restrict__ egk,
                                                 u16* __restrict__ Ob,
                                                 float* __restrict__ Sst) {
  __shared__ __align__(16) u16 Ks[2][128 * 64];  // [k][d], swizzled (16KB ea)
  __shared__ __align__(16) u16 Vs[2][64 * 128];  // [d][k], swizzled (16KB ea)
  __shared__ __align__(16) u32 Ps[4][16][64];    // per-wave P pairs (16KB)
  const int i = blockIdx.x;
  const int lb = ((i & 7) << 6) | (i >> 3);  // XCD-bijective: 4 bh per XCD
  const int bh = lb >> 4, qblk = lb & 15;
  const int t = threadIdx.x, lane = t & 63, w = t >> 6;
  const int lm = lane & 15, lg = lane >> 4;
  const int b = bh >> 4, h = bh & 15;
  const size_t bhS = (size_t)bh << 10;
  const int qb = qblk * 64 + w * 16;

#define STAGE(buf, k0)                                                         \
  {                                                                            \
    int rowK = t >> 3, cK = t & 7;                                             \
    int rowV = t >> 4, cV = t & 15;                                            \
    _Pragma("unroll") for (int i2 = 0; i2 < 4; ++i2) {                         \
      int rr = rowK + 32 * i2;                                                 \
      gload_lds16(Kt + (bhS + (k0) + rr) * 64 + ((cK ^ (rr & 7)) * 8),         \
                  (char*)Ks[buf] + t * 16 + i2 * 4096);                        \
      int dd2 = rowV + 16 * i2;                                                \
      gload_lds16(Vt + ((size_t)bh * 64 + dd2) * 1024 + (k0) +                 \
                      ((cV ^ (dd2 & 15)) * 8),                                 \
                  (char*)Vs[buf] + t * 16 + i2 * 4096);                        \
    }                                                                          \
  }

  bf16x8 qf[2];
#pragma unroll
  for (int ks = 0; ks < 2; ++ks)
    qf[ks] = *(const bf16x8*)(Q + (bhS + qb + lm) * 64 + ks * 32 + lg * 8);
  const float efql = efq[bhS + qb + lm];

  f32x4 Oacc[4] = {};
  float m_r = -1e30f, l_r = 0.f, W_r = 0.f;

  STAGE(0, 0);
  f32x4 egN[8];
#pragma unroll
  for (int nt = 0; nt < 8; ++nt)
    egN[nt] = *(const f32x4*)&egk[bhS + nt * 16 + lg * 4];
  __syncthreads();

  for (int kt = 0; kt < 8; ++kt) {
    const int cur = kt & 1;
    if (kt < 7) STAGE(cur ^ 1, (kt + 1) * 128);

    // swapped QK^T: lane owns q = lm; k = nt*16 + lg*4 + r
    f32x4 c_[8];
#pragma unroll
    for (int nt = 0; nt < 8; ++nt) {
      c_[nt] = (f32x4){0.f, 0.f, 0.f, 0.f};
#pragma unroll
      for (int ks = 0; ks < 2; ++ks) {
        int row = nt * 16 + lm;
        int byo = (((ks * 4 + lg) ^ (row & 7)) << 4);
        bf16x8 kb = *(const bf16x8*)((const char*)Ks[cur] + row * 128 + byo);
        c_[nt] = MFMA16(kb, qf[ks], c_[nt]);
      }
    }

    // gate: v = s - log1p(efq*egk) via poly (x <= 0.402)
    float v_[8][4];
    float lmax = -3e38f;
#pragma unroll
    for (int nt = 0; nt < 8; ++nt) {
      f32x4 eg = egN[nt];
#pragma unroll
      for (int r = 0; r < 4; ++r) {
        float xg = efql * eg[r];
        float lsig =
            -xg * (1.f - xg * (0.5f - xg * (0.333333333f - xg * (0.25f - 0.2f * xg))));
        float vv = c_[nt][r] + lsig;
        v_[nt][r] = vv;
        lmax = fmaxf(lmax, vv);
      }
    }
    // prefetch next tile's egk into registers (consumed next iteration)
    if (kt < 7) {
#pragma unroll
      for (int nt = 0; nt < 8; ++nt)
        egN[nt] = *(const f32x4*)&egk[bhS + (kt + 1) * 128 + nt * 16 + lg * 4];
    }
    lmax = fmaxf(lmax, __shfl_xor(lmax, 16));
    lmax = fmaxf(lmax, __shfl_xor(lmax, 32));

    // defer-max (T13): entropy is shift-invariant
    if (__any(lmax > m_r + 5.f)) {
      float mn = fmaxf(m_r, lmax);
      float dd = m_r - mn;
      float sc = __expf(dd);
      W_r = sc * (W_r + dd * l_r);
      l_r *= sc;
      m_r = mn;
      float scO[4];
#pragma unroll
      for (int r = 0; r < 4; ++r) scO[r] = __shfl(sc, (lane & 48) | (lg * 4 + r));
#pragma unroll
      for (int dt = 0; dt < 4; ++dt)
#pragma unroll
        for (int r = 0; r < 4; ++r) Oacc[dt][r] *= scO[r];
    }

    // p = exp(v-m); accumulate l, W; pack to bf16 pairs
    float psum = 0.f, wsum = 0.f;
    u32 pw[16];
#pragma unroll
    for (int nt = 0; nt < 8; ++nt) {
      float p_[4];
#pragma unroll
      for (int r = 0; r < 4; ++r) {
        float sh = v_[nt][r] - m_r;
        float p = __expf(sh);
        p_[r] = p;
        psum += p;
        wsum = fmaf(p, sh, wsum);
      }
      asm("v_cvt_pk_bf16_f32 %0, %1, %2" : "=v"(pw[nt * 2 + 0]) : "v"(p_[0]), "v"(p_[1]));
      asm("v_cvt_pk_bf16_f32 %0, %1, %2" : "=v"(pw[nt * 2 + 1]) : "v"(p_[2]), "v"(p_[3]));
    }
    psum += __shfl_xor(psum, 16);
    psum += __shfl_xor(psum, 32);
    wsum += __shfl_xor(wsum, 16);
    wsum += __shfl_xor(wsum, 32);
    l_r += psum;
    W_r += wsum;

    // P -> per-wave LDS (swizzled u32 pairs)
    u32* prow = &Ps[w][lm][0];
    const int sw = (lm & 7) << 2;
#pragma unroll
    for (int nt = 0; nt < 8; ++nt) {
      int idx = (nt * 8 + lg * 2) ^ sw;
      uint2 pr;
      pr.x = pw[nt * 2 + 0];
      pr.y = pw[nt * 2 + 1];
      *(uint2*)(prow + idx) = pr;
    }

    bf16x8 pa[4];
#pragma unroll
    for (int ks = 0; ks < 4; ++ks) {
      int idx = (ks * 16 + lg * 4) ^ sw;
      pa[ks] = *(const bf16x8*)(prow + idx);
    }
#pragma unroll
    for (int dt = 0; dt < 4; ++dt) {
#pragma unroll
      for (int ks = 0; ks < 4; ++ks) {
        int row = dt * 16 + lm;
        int byo = (((ks * 4 + lg) ^ (row & 15)) << 4);
        bf16x8 vb = *(const bf16x8*)((const char*)Vs[cur] + row * 256 + byo);
        Oacc[dt] = MFMA16(pa[ks], vb, Oacc[dt]);
      }
    }
    __syncthreads();  // drains vmcnt(0): next buffer staged & ready
  }

  float invl = 1.f / l_r;
  float entv = __logf(l_r) - W_r * invl;
  float invO[4];
#pragma unroll
  for (int r = 0; r < 4; ++r) invO[r] = __shfl(invl, (lane & 48) | (lg * 4 + r));
#pragma unroll
  for (int dt = 0; dt < 4; ++dt)
#pragma unroll
    for (int r = 0; r < 4; ++r) {
      int srow = qb + lg * 4 + r;
      int col = h * 64 + dt * 16 + lm;
      Ob[(size_t)(b * 1024 + srow) * 1024 + col] = f2bf(Oacc[dt][r] * invO[r]);
    }
  if (lg == 0) Sst[bhS + qb + lm] = entv;
#undef STAGE
}

// ---------------- workspace layout (bytes) ----------------
static constexpr size_t OFF_XB = 0;                    // 4 MB  x bf16
static constexpr size_t OFF_WB = 4ull << 20;           // 6 MB  Wq|Wk|Wv bf16
static constexpr size_t OFF_Q = 10ull << 20;           // 4 MB  Q bf16, pre-scaled
static constexpr size_t OFF_K = 14ull << 20;           // 4 MB  K bf16
static constexpr size_t OFF_OB = 18ull << 20;          // 4 MB  attn out bf16
static constexpr size_t OFF_VT = 22ull << 20;          // 4 MB  V^T bf16 (B,H,64,S)
static constexpr size_t OFF_WOB = 26ull << 20;         // 2 MB  Wo bf16
static constexpr size_t OFF_FQ = 28ull << 20;          // 128 KB f32 exp(-fq)
static constexpr size_t OFF_GK = (28ull << 20) + (128ull << 10);  // 128 KB f32 exp(-gk)

extern "C" void kernel_launch(void* const* d_in, const int* in_sizes, int n_in,
                              void* d_out, int out_size, void* d_ws, size_t ws_size,
                              hipStream_t stream) {
  const float* x = (const float*)d_in[0];
  const float* ent = (const float*)d_in[1];
  const float* Wq = (const float*)d_in[2];
  const float* Wk = (const float*)d_in[3];
  const float* Wv = (const float*)d_in[4];
  const float* Wo = (const float*)d_in[5];
  (void)in_sizes; (void)n_in; (void)out_size; (void)ws_size;

  char* ws = (char*)d_ws;
  u16* xb = (u16*)(ws + OFF_XB);
  u16* Wb = (u16*)(ws + OFF_WB);
  u16* Qb = (u16*)(ws + OFF_Q);
  u16* Kb = (u16*)(ws + OFF_K);
  u16* Ob = (u16*)(ws + OFF_OB);
  u16* Vtb = (u16*)(ws + OFF_VT);
  u16* Wob = (u16*)(ws + OFF_WOB);
  float* efqd = (float*)(ws + OFF_FQ);
  float* egkd = (float*)(ws + OFF_GK);
  float* outp = (float*)d_out;
  float* Sst = outp + 2u * 1024u * 1024u;

  k_prep<<<3200, 256, 0, stream>>>(x, Wq, Wk, Wv, Wo, ent, xb, Wb, Wob, efqd);

  k_gemm<128, 128, 0><<<dim3(24, 16), 256, 0, stream>>>(xb, Wb, 1024, Qb, Kb, Vtb,
                                                        egkd, nullptr);

  k_attn<<<512, 256, 0, stream>>>(Qb, Kb, Vtb, efqd, egkd, Ob, Sst);

  k_gemm<64, 128, 1><<<dim3(8, 32), 256, 0, stream>>>(Ob, Wob, 1024, nullptr, nullptr,
                                                      nullptr, nullptr, outp);
}

// Round 4
// 68.012 us; speedup vs baseline: 2.1568x; 1.1591x over previous
//
#include <hip/hip_runtime.h>
#include <cstdint>

#define DEVINL __device__ __forceinline__

typedef __attribute__((ext_vector_type(8))) short bf16x8;
typedef __attribute__((ext_vector_type(4))) float f32x4;
typedef __attribute__((ext_vector_type(8))) unsigned short u16x8;
typedef unsigned short u16;
typedef unsigned int u32;

#define MFMA16(a, b, c) __builtin_amdgcn_mfma_f32_16x16x32_bf16(a, b, c, 0, 0, 0)

DEVINL u16 f2bf(float x) {
  u32 u = __builtin_bit_cast(u32, x);
  u += 0x7FFFu + ((u >> 16) & 1u);
  return (u16)(u >> 16);
}
DEVINL float bf2f(u16 s) {
  u32 u = ((u32)s) << 16;
  return __builtin_bit_cast(float, u);
}
DEVINL void gload_lds16(const void* g, void* l) {
  __builtin_amdgcn_global_load_lds(
      (const __attribute__((address_space(1))) unsigned int*)g,
      (__attribute__((address_space(3))) unsigned int*)l, 16, 0, 0);
}

// ---------------- fused prologue: f32->bf16 converts + efq ------------------
__global__ __launch_bounds__(256) void k_prep(const float* __restrict__ x,
                                              const float* __restrict__ Wq,
                                              const float* __restrict__ Wk,
                                              const float* __restrict__ Wv,
                                              const float* __restrict__ Wo,
                                              const float* __restrict__ ent,
                                              u16* __restrict__ xb,
                                              u16* __restrict__ Wb,
                                              u16* __restrict__ Wob,
                                              float* __restrict__ efq) {
  const int bid = blockIdx.x;
  if (bid < 3072) {
    const float* src;
    u16* dst;
    int base;
    if (bid < 1024)      { src = x;  dst = xb;            base = bid; }
    else if (bid < 1536) { src = Wq; dst = Wb;            base = bid - 1024; }
    else if (bid < 2048) { src = Wk; dst = Wb + (1u<<20); base = bid - 1536; }
    else if (bid < 2560) { src = Wv; dst = Wb + (2u<<20); base = bid - 2048; }
    else                 { src = Wo; dst = Wob;           base = bid - 2560; }
    int i = base * 256 + threadIdx.x;
    const float4* s4 = (const float4*)src;
    float4 a = s4[2 * i], b = s4[2 * i + 1];
    u16x8 o;
    o[0] = f2bf(a.x); o[1] = f2bf(a.y); o[2] = f2bf(a.z); o[3] = f2bf(a.w);
    o[4] = f2bf(b.x); o[5] = f2bf(b.y); o[6] = f2bf(b.z); o[7] = f2bf(b.w);
    *(u16x8*)(dst + 8 * i) = o;
  } else {
    int i = (bid - 3072) * 256 + threadIdx.x;
    float e = ent[i];
    float Et = 1.f / (1.f + __expf(-5.f * (e - 0.3f)));
    efq[i] = __expf(-(5.f * Et - 0.3f * e));
  }
}

// ---------------- tiled bf16 GEMM, C = A * B^T, BK=64, dbuf LDS, 2-phase -----
// 1D grid, XCD-bijective swizzle. M fixed = 2048.
// MODE 0 (128x128): QKV epilogues (Q*0.125 -> Qo; K -> Ko + egk; V -> Vt).
// MODE 1: f32 store to Cout (N=1024).
template <int BM, int BN, int NDIM, int MODE>
__global__ __launch_bounds__(256) void k_gemm(const u16* __restrict__ A,
                                              const u16* __restrict__ Bw,
                                              int Kdim, u16* __restrict__ Qo,
                                              u16* __restrict__ Ko,
                                              u16* __restrict__ Vt,
                                              float* __restrict__ egk_out,
                                              float* __restrict__ Cout) {
  constexpr int MT = BM / 32, NT = BN / 32;
  constexpr int MB = 2048 / BM, NB = NDIM / BN;
  constexpr int CPX = MB * NB / 8;
  __shared__ __align__(16) u16 SM[2][(BM + BN) * 64];
  const int t = threadIdx.x;
  const int lb = (blockIdx.x & 7) * CPX + (blockIdx.x >> 3);
  const int m0 = (lb % MB) * BM, n0 = (lb / MB) * BN;
  const int lane = t & 63, w = t >> 6;
  const int wr = w >> 1, wc = w & 1, lm = lane & 15, lg = lane >> 4;
  const int rs = t >> 3, cs = t & 7;
  f32x4 acc[MT][NT] = {};

#define GSTAGE(buf, kt)                                                        \
  {                                                                            \
    u16* As_ = SM[buf];                                                        \
    u16* Bs_ = SM[buf] + BM * 64;                                              \
    _Pragma("unroll") for (int i = 0; i < BM / 32; ++i) {                      \
      int rr = rs + 32 * i;                                                    \
      gload_lds16(A + (size_t)(m0 + rr) * Kdim + (kt) + ((cs ^ (rr & 7)) * 8), \
                  (char*)As_ + t * 16 + i * 4096);                             \
    }                                                                          \
    _Pragma("unroll") for (int i = 0; i < BN / 32; ++i) {                      \
      int rr = rs + 32 * i;                                                    \
      gload_lds16(Bw + (size_t)(n0 + rr) * Kdim + (kt) + ((cs ^ (rr & 7)) * 8),\
                  (char*)Bs_ + t * 16 + i * 4096);                             \
    }                                                                          \
  }

  GSTAGE(0, 0);
  __syncthreads();
  const int nk = Kdim >> 6;
  for (int ki = 0; ki < nk; ++ki) {
    const int cur = ki & 1;
    if (ki + 1 < nk) GSTAGE(cur ^ 1, (ki + 1) * 64);
    const u16* As = SM[cur];
    const u16* Bs = SM[cur] + BM * 64;
#pragma unroll
    for (int ks = 0; ks < 2; ++ks) {
      bf16x8 af[MT], bf[NT];
#pragma unroll
      for (int mt = 0; mt < MT; ++mt) {
        int row = wr * (BM / 2) + mt * 16 + lm;
        af[mt] = *(const bf16x8*)((const char*)As + row * 128 +
                                  (((ks * 4 + lg) ^ (row & 7)) << 4));
      }
#pragma unroll
      for (int nt = 0; nt < NT; ++nt) {
        int row = wc * (BN / 2) + nt * 16 + lm;
        bf[nt] = *(const bf16x8*)((const char*)Bs + row * 128 +
                                  (((ks * 4 + lg) ^ (row & 7)) << 4));
      }
#pragma unroll
      for (int mt = 0; mt < MT; ++mt)
#pragma unroll
        for (int nt = 0; nt < NT; ++nt)
          acc[mt][nt] = MFMA16(af[mt], bf[nt], acc[mt][nt]);
    }
    __syncthreads();  // drains this iter's prefetch (had full MFMA phase in flight)
  }
#undef GSTAGE

  if (MODE == 1) {
#pragma unroll
    for (int mt = 0; mt < MT; ++mt)
#pragma unroll
      for (int nt = 0; nt < NT; ++nt)
#pragma unroll
        for (int r = 0; r < 4; ++r) {
          int m = m0 + wr * (BM / 2) + mt * 16 + lg * 4 + r;
          int n = n0 + wc * (BN / 2) + nt * 16 + lm;
          Cout[(size_t)m * 1024 + n] = acc[mt][nt][r];
        }
    return;
  }

  // MODE 0 epilogue: region by n0
  const int region = n0 >> 10;  // 0=Q 1=K 2=V
  const int b = m0 >> 10, s0 = m0 & 1023;
  if (region < 2) {
    u16* dst = region == 0 ? Qo : Ko;
    const float scl = region == 0 ? 0.125f : 1.f;
#pragma unroll
    for (int mt = 0; mt < MT; ++mt)
#pragma unroll
      for (int nt = 0; nt < NT; ++nt)
#pragma unroll
        for (int r = 0; r < 4; ++r) {
          int m = m0 + wr * 64 + mt * 16 + lg * 4 + r;
          int n = n0 + wc * 64 + nt * 16 + lm;
          int e = n & 1023, h = e >> 6, d = e & 63;
          dst[(size_t)(((b << 4) + h) * 1024 + (m & 1023)) * 64 + d] =
              f2bf(acc[mt][nt][r] * scl);
        }
    if (region == 1) {
      int hh = ((n0 - 1024) >> 6) + wc;
#pragma unroll
      for (int mt = 0; mt < MT; ++mt)
#pragma unroll
        for (int r = 0; r < 4; ++r) {
          float ss = 0.f;
#pragma unroll
          for (int nt = 0; nt < NT; ++nt) ss += acc[mt][nt][r] * acc[mt][nt][r];
          ss += __shfl_xor(ss, 1);
          ss += __shfl_xor(ss, 2);
          ss += __shfl_xor(ss, 4);
          ss += __shfl_xor(ss, 8);
          if (lm == 0) {
            int s = s0 + wr * 64 + mt * 16 + lg * 4 + r;
            float g = 1.4f * fminf(ss * (1.f / 64.f), 2.f);
            egk_out[(size_t)(((b << 4) + hh)) * 1024 + s] = __expf(-g);
          }
        }
    }
  } else {
    // V: transpose via LDS (one head per wave-column, two passes)
    u16* tile = SM[0];  // [64][128] u16, XOR-swizzled on m
#pragma unroll
    for (int half = 0; half < 2; ++half) {
      if (wc == half) {
#pragma unroll
        for (int mt = 0; mt < MT; ++mt)
#pragma unroll
          for (int nt = 0; nt < NT; ++nt)
#pragma unroll
            for (int r = 0; r < 4; ++r) {
              int d = nt * 16 + lm;
              int mloc = wr * 64 + mt * 16 + lg * 4 + r;
              tile[d * 128 + (mloc ^ ((d & 7) << 3))] = f2bf(acc[mt][nt][r]);
            }
      }
      __syncthreads();
      int hh = ((n0 - 2048) >> 6) + half;
#pragma unroll
      for (int j = 0; j < 4; ++j) {
        int dd = (t >> 4) + 16 * j, mc = t & 15;
        u16x8 v = *(const u16x8*)&tile[dd * 128 + ((mc * 8) ^ ((dd & 7) << 3))];
        *(u16x8*)(Vt + ((size_t)(((b << 4) + hh) * 64 + dd)) * 1024 + s0 + mc * 8) = v;
      }
      __syncthreads();
    }
  }
}

// ---------------- fused gated flash attention + entropy ----------------------
// grid 512 (XCD-swizzled); 4 waves/block, 16 q-rows/wave, KVBLK=128, dbuf LDS.
__global__ __launch_bounds__(256, 2) void k_attn(const u16* __restrict__ Q,
                                                 const u16* __restrict__ Kt,
                                                 const u16* __restrict__ Vt,
                                                 const float* __restrict__ efq,
                                                 const float* __restrict__ egk,
                                                 u16* __restrict__ Ob,
                                                 float* __restrict__ Sst) {
  __shared__ __align__(16) u16 Ks[2][128 * 64];  // [k][d], swizzled (16KB ea)
  __shared__ __align__(16) u16 Vs[2][64 * 128];  // [d][k], swizzled (16KB ea)
  __shared__ __align__(16) u32 Ps[4][16][64];    // per-wave P pairs (16KB)
  const int i = blockIdx.x;
  const int lb = ((i & 7) << 6) | (i >> 3);  // XCD-bijective: 4 bh per XCD
  const int bh = lb >> 4, qblk = lb & 15;
  const int t = threadIdx.x, lane = t & 63, w = t >> 6;
  const int lm = lane & 15, lg = lane >> 4;
  const int b = bh >> 4, h = bh & 15;
  const size_t bhS = (size_t)bh << 10;
  const int qb = qblk * 64 + w * 16;

#define STAGE(buf, k0)                                                         \
  {                                                                            \
    int rowK = t >> 3, cK = t & 7;                                             \
    int rowV = t >> 4, cV = t & 15;                                            \
    _Pragma("unroll") for (int i2 = 0; i2 < 4; ++i2) {                         \
      int rr = rowK + 32 * i2;                                                 \
      gload_lds16(Kt + (bhS + (k0) + rr) * 64 + ((cK ^ (rr & 7)) * 8),         \
                  (char*)Ks[buf] + t * 16 + i2 * 4096);                        \
      int dd2 = rowV + 16 * i2;                                                \
      gload_lds16(Vt + ((size_t)bh * 64 + dd2) * 1024 + (k0) +                 \
                      ((cV ^ (dd2 & 15)) * 8),                                 \
                  (char*)Vs[buf] + t * 16 + i2 * 4096);                        \
    }                                                                          \
  }

  bf16x8 qf[2];
#pragma unroll
  for (int ks = 0; ks < 2; ++ks)
    qf[ks] = *(const bf16x8*)(Q + (bhS + qb + lm) * 64 + ks * 32 + lg * 8);
  const float efql = efq[bhS + qb + lm];

  f32x4 Oacc[4] = {};
  float m_r = -1e30f, l_r = 0.f, W_r = 0.f;

  STAGE(0, 0);
  f32x4 egN[8];
#pragma unroll
  for (int nt = 0; nt < 8; ++nt)
    egN[nt] = *(const f32x4*)&egk[bhS + nt * 16 + lg * 4];
  __syncthreads();

  for (int kt = 0; kt < 8; ++kt) {
    const int cur = kt & 1;
    if (kt < 7) STAGE(cur ^ 1, (kt + 1) * 128);

    // swapped QK^T: lane owns q = lm; k = nt*16 + lg*4 + r
    f32x4 c_[8];
#pragma unroll
    for (int nt = 0; nt < 8; ++nt) {
      c_[nt] = (f32x4){0.f, 0.f, 0.f, 0.f};
#pragma unroll
      for (int ks = 0; ks < 2; ++ks) {
        int row = nt * 16 + lm;
        int byo = (((ks * 4 + lg) ^ (row & 7)) << 4);
        bf16x8 kb = *(const bf16x8*)((const char*)Ks[cur] + row * 128 + byo);
        c_[nt] = MFMA16(kb, qf[ks], c_[nt]);
      }
    }

    // gate: v = s - log1p(efq*egk) via poly (x <= 0.402)
    float v_[8][4];
    float lmax = -3e38f;
#pragma unroll
    for (int nt = 0; nt < 8; ++nt) {
      f32x4 eg = egN[nt];
#pragma unroll
      for (int r = 0; r < 4; ++r) {
        float xg = efql * eg[r];
        float lsig =
            -xg * (1.f - xg * (0.5f - xg * (0.333333333f - xg * (0.25f - 0.2f * xg))));
        float vv = c_[nt][r] + lsig;
        v_[nt][r] = vv;
        lmax = fmaxf(lmax, vv);
      }
    }
    if (kt < 7) {
#pragma unroll
      for (int nt = 0; nt < 8; ++nt)
        egN[nt] = *(const f32x4*)&egk[bhS + (kt + 1) * 128 + nt * 16 + lg * 4];
    }
    lmax = fmaxf(lmax, __shfl_xor(lmax, 16));
    lmax = fmaxf(lmax, __shfl_xor(lmax, 32));

    // defer-max (T13): entropy is shift-invariant
    if (__any(lmax > m_r + 5.f)) {
      float mn = fmaxf(m_r, lmax);
      float dd = m_r - mn;
      float sc = __expf(dd);
      W_r = sc * (W_r + dd * l_r);
      l_r *= sc;
      m_r = mn;
      float scO[4];
#pragma unroll
      for (int r = 0; r < 4; ++r) scO[r] = __shfl(sc, (lane & 48) | (lg * 4 + r));
#pragma unroll
      for (int dt = 0; dt < 4; ++dt)
#pragma unroll
        for (int r = 0; r < 4; ++r) Oacc[dt][r] *= scO[r];
    }

    // p = exp(v-m); accumulate l, W; pack to bf16 pairs
    float psum = 0.f, wsum = 0.f;
    u32 pw[16];
#pragma unroll
    for (int nt = 0; nt < 8; ++nt) {
      float p_[4];
#pragma unroll
      for (int r = 0; r < 4; ++r) {
        float sh = v_[nt][r] - m_r;
        float p = __expf(sh);
        p_[r] = p;
        psum += p;
        wsum = fmaf(p, sh, wsum);
      }
      asm("v_cvt_pk_bf16_f32 %0, %1, %2" : "=v"(pw[nt * 2 + 0]) : "v"(p_[0]), "v"(p_[1]));
      asm("v_cvt_pk_bf16_f32 %0, %1, %2" : "=v"(pw[nt * 2 + 1]) : "v"(p_[2]), "v"(p_[3]));
    }
    psum += __shfl_xor(psum, 16);
    psum += __shfl_xor(psum, 32);
    wsum += __shfl_xor(wsum, 16);
    wsum += __shfl_xor(wsum, 32);
    l_r += psum;
    W_r += wsum;

    // P -> per-wave LDS (swizzled u32 pairs)
    u32* prow = &Ps[w][lm][0];
    const int sw = (lm & 7) << 2;
#pragma unroll
    for (int nt = 0; nt < 8; ++nt) {
      int idx = (nt * 8 + lg * 2) ^ sw;
      uint2 pr;
      pr.x = pw[nt * 2 + 0];
      pr.y = pw[nt * 2 + 1];
      *(uint2*)(prow + idx) = pr;
    }

    bf16x8 pa[4];
#pragma unroll
    for (int ks = 0; ks < 4; ++ks) {
      int idx = (ks * 16 + lg * 4) ^ sw;
      pa[ks] = *(const bf16x8*)(prow + idx);
    }
#pragma unroll
    for (int dt = 0; dt < 4; ++dt) {
#pragma unroll
      for (int ks = 0; ks < 4; ++ks) {
        int row = dt * 16 + lm;
        int byo = (((ks * 4 + lg) ^ (row & 15)) << 4);
        bf16x8 vb = *(const bf16x8*)((const char*)Vs[cur] + row * 256 + byo);
        Oacc[dt] = MFMA16(pa[ks], vb, Oacc[dt]);
      }
    }
    __syncthreads();  // drains vmcnt(0): next buffer staged & ready
  }

  float invl = 1.f / l_r;
  float entv = __logf(l_r) - W_r * invl;
  float invO[4];
#pragma unroll
  for (int r = 0; r < 4; ++r) invO[r] = __shfl(invl, (lane & 48) | (lg * 4 + r));
#pragma unroll
  for (int dt = 0; dt < 4; ++dt)
#pragma unroll
    for (int r = 0; r < 4; ++r) {
      int srow = qb + lg * 4 + r;
      int col = h * 64 + dt * 16 + lm;
      Ob[(size_t)(b * 1024 + srow) * 1024 + col] = f2bf(Oacc[dt][r] * invO[r]);
    }
  if (lg == 0) Sst[bhS + qb + lm] = entv;
#undef STAGE
}

// ---------------- workspace layout (bytes) ----------------
static constexpr size_t OFF_XB = 0;                    // 4 MB  x bf16
static constexpr size_t OFF_WB = 4ull << 20;           // 6 MB  Wq|Wk|Wv bf16
static constexpr size_t OFF_Q = 10ull << 20;           // 4 MB  Q bf16, pre-scaled
static constexpr size_t OFF_K = 14ull << 20;           // 4 MB  K bf16
static constexpr size_t OFF_OB = 18ull << 20;          // 4 MB  attn out bf16
static constexpr size_t OFF_VT = 22ull << 20;          // 4 MB  V^T bf16 (B,H,64,S)
static constexpr size_t OFF_WOB = 26ull << 20;         // 2 MB  Wo bf16
static constexpr size_t OFF_FQ = 28ull << 20;          // 128 KB f32 exp(-fq)
static constexpr size_t OFF_GK = (28ull << 20) + (128ull << 10);  // 128 KB f32 exp(-gk)

extern "C" void kernel_launch(void* const* d_in, const int* in_sizes, int n_in,
                              void* d_out, int out_size, void* d_ws, size_t ws_size,
                              hipStream_t stream) {
  const float* x = (const float*)d_in[0];
  const float* ent = (const float*)d_in[1];
  const float* Wq = (const float*)d_in[2];
  const float* Wk = (const float*)d_in[3];
  const float* Wv = (const float*)d_in[4];
  const float* Wo = (const float*)d_in[5];
  (void)in_sizes; (void)n_in; (void)out_size; (void)ws_size;

  char* ws = (char*)d_ws;
  u16* xb = (u16*)(ws + OFF_XB);
  u16* Wb = (u16*)(ws + OFF_WB);
  u16* Qb = (u16*)(ws + OFF_Q);
  u16* Kb = (u16*)(ws + OFF_K);
  u16* Ob = (u16*)(ws + OFF_OB);
  u16* Vtb = (u16*)(ws + OFF_VT);
  u16* Wob = (u16*)(ws + OFF_WOB);
  float* efqd = (float*)(ws + OFF_FQ);
  float* egkd = (float*)(ws + OFF_GK);
  float* outp = (float*)d_out;
  float* Sst = outp + 2u * 1024u * 1024u;

  k_prep<<<3200, 256, 0, stream>>>(x, Wq, Wk, Wv, Wo, ent, xb, Wb, Wob, efqd);

  k_gemm<128, 128, 3072, 0><<<384, 256, 0, stream>>>(xb, Wb, 1024, Qb, Kb, Vtb,
                                                     egkd, nullptr);

  k_attn<<<512, 256, 0, stream>>>(Qb, Kb, Vtb, efqd, egkd, Ob, Sst);

  k_gemm<64, 64, 1024, 1><<<512, 256, 0, stream>>>(Ob, Wob, 1024, nullptr, nullptr,
                                                   nullptr, nullptr, outp);
}

// Round 5
// 68.004 us; speedup vs baseline: 2.1570x; 1.0001x over previous
//
#include <hip/hip_runtime.h>
#include <cstdint>

#define DEVINL __device__ __forceinline__

typedef __attribute__((ext_vector_type(8))) short bf16x8;
typedef __attribute__((ext_vector_type(4))) float f32x4;
typedef __attribute__((ext_vector_type(8))) unsigned short u16x8;
typedef unsigned short u16;
typedef unsigned int u32;

#define MFMA16(a, b, c) __builtin_amdgcn_mfma_f32_16x16x32_bf16(a, b, c, 0, 0, 0)

// log2-domain constants
#define LOG2E 1.4426950408889634f
#define LN2 0.69314718055994531f

DEVINL u16 f2bf(float x) {
  u32 u = __builtin_bit_cast(u32, x);
  u += 0x7FFFu + ((u >> 16) & 1u);
  return (u16)(u >> 16);
}
DEVINL float bf2f(u16 s) {
  u32 u = ((u32)s) << 16;
  return __builtin_bit_cast(float, u);
}
DEVINL float exp2fast(float x) {  // v_exp_f32 IS 2^x
  float r;
  asm("v_exp_f32 %0, %1" : "=v"(r) : "v"(x));
  return r;
}
DEVINL void gload_lds16(const void* g, void* l) {
  __builtin_amdgcn_global_load_lds(
      (const __attribute__((address_space(1))) unsigned int*)g,
      (__attribute__((address_space(3))) unsigned int*)l, 16, 0, 0);
}

// ---------------- fused prologue: f32->bf16 converts + efq ------------------
__global__ __launch_bounds__(256) void k_prep(const float* __restrict__ x,
                                              const float* __restrict__ Wq,
                                              const float* __restrict__ Wk,
                                              const float* __restrict__ Wv,
                                              const float* __restrict__ Wo,
                                              const float* __restrict__ ent,
                                              u16* __restrict__ xb,
                                              u16* __restrict__ Wb,
                                              u16* __restrict__ Wob,
                                              float* __restrict__ efq) {
  const int bid = blockIdx.x;
  if (bid < 3072) {
    const float* src;
    u16* dst;
    int base;
    if (bid < 1024)      { src = x;  dst = xb;            base = bid; }
    else if (bid < 1536) { src = Wq; dst = Wb;            base = bid - 1024; }
    else if (bid < 2048) { src = Wk; dst = Wb + (1u<<20); base = bid - 1536; }
    else if (bid < 2560) { src = Wv; dst = Wb + (2u<<20); base = bid - 2048; }
    else                 { src = Wo; dst = Wob;           base = bid - 2560; }
    int i = base * 256 + threadIdx.x;
    const float4* s4 = (const float4*)src;
    float4 a = s4[2 * i], b = s4[2 * i + 1];
    u16x8 o;
    o[0] = f2bf(a.x); o[1] = f2bf(a.y); o[2] = f2bf(a.z); o[3] = f2bf(a.w);
    o[4] = f2bf(b.x); o[5] = f2bf(b.y); o[6] = f2bf(b.z); o[7] = f2bf(b.w);
    *(u16x8*)(dst + 8 * i) = o;
  } else {
    int i = (bid - 3072) * 256 + threadIdx.x;
    float e = ent[i];
    float Et = 1.f / (1.f + __expf(-5.f * (e - 0.3f)));
    // efq2 = log2e * exp(-f(q)): folds the base-2 conversion into the gate
    efq[i] = LOG2E * __expf(-(5.f * Et - 0.3f * e));
  }
}

// ---------------- tiled bf16 GEMM, C = A * B^T, BK=64, dbuf LDS, 2-phase -----
// 1D grid, XCD-bijective swizzle. M fixed = 2048.
// MODE 0 (BM=64,BN=128): QKV epilogues (Q*0.125*log2e -> Qo; K -> Ko + egk; V -> Vt).
// MODE 1: f32 store to Cout (N=1024).
template <int BM, int BN, int NDIM, int MODE>
__global__ __launch_bounds__(256) void k_gemm(const u16* __restrict__ A,
                                              const u16* __restrict__ Bw,
                                              int Kdim, u16* __restrict__ Qo,
                                              u16* __restrict__ Ko,
                                              u16* __restrict__ Vt,
                                              float* __restrict__ egk_out,
                                              float* __restrict__ Cout) {
  constexpr int MT = BM / 32, NT = BN / 32;
  constexpr int MB = 2048 / BM, NB = NDIM / BN;
  constexpr int CPX = MB * NB / 8;
  __shared__ __align__(16) u16 SM[2][(BM + BN) * 64];
  const int t = threadIdx.x;
  const int lb = (blockIdx.x & 7) * CPX + (blockIdx.x >> 3);
  const int m0 = (lb % MB) * BM, n0 = (lb / MB) * BN;
  const int lane = t & 63, w = t >> 6;
  const int wr = w >> 1, wc = w & 1, lm = lane & 15, lg = lane >> 4;
  const int rs = t >> 3, cs = t & 7;
  f32x4 acc[MT][NT] = {};

#define GSTAGE(buf, kt)                                                        \
  {                                                                            \
    u16* As_ = SM[buf];                                                        \
    u16* Bs_ = SM[buf] + BM * 64;                                              \
    _Pragma("unroll") for (int i = 0; i < BM / 32; ++i) {                      \
      int rr = rs + 32 * i;                                                    \
      gload_lds16(A + (size_t)(m0 + rr) * Kdim + (kt) + ((cs ^ (rr & 7)) * 8), \
                  (char*)As_ + t * 16 + i * 4096);                             \
    }                                                                          \
    _Pragma("unroll") for (int i = 0; i < BN / 32; ++i) {                      \
      int rr = rs + 32 * i;                                                    \
      gload_lds16(Bw + (size_t)(n0 + rr) * Kdim + (kt) + ((cs ^ (rr & 7)) * 8),\
                  (char*)Bs_ + t * 16 + i * 4096);                             \
    }                                                                          \
  }

  GSTAGE(0, 0);
  __syncthreads();
  const int nk = Kdim >> 6;
  for (int ki = 0; ki < nk; ++ki) {
    const int cur = ki & 1;
    if (ki + 1 < nk) GSTAGE(cur ^ 1, (ki + 1) * 64);
    const u16* As = SM[cur];
    const u16* Bs = SM[cur] + BM * 64;
#pragma unroll
    for (int ks = 0; ks < 2; ++ks) {
      bf16x8 af[MT], bf[NT];
#pragma unroll
      for (int mt = 0; mt < MT; ++mt) {
        int row = wr * (BM / 2) + mt * 16 + lm;
        af[mt] = *(const bf16x8*)((const char*)As + row * 128 +
                                  (((ks * 4 + lg) ^ (row & 7)) << 4));
      }
#pragma unroll
      for (int nt = 0; nt < NT; ++nt) {
        int row = wc * (BN / 2) + nt * 16 + lm;
        bf[nt] = *(const bf16x8*)((const char*)Bs + row * 128 +
                                  (((ks * 4 + lg) ^ (row & 7)) << 4));
      }
#pragma unroll
      for (int mt = 0; mt < MT; ++mt)
#pragma unroll
        for (int nt = 0; nt < NT; ++nt)
          acc[mt][nt] = MFMA16(af[mt], bf[nt], acc[mt][nt]);
    }
    __syncthreads();  // drains this iter's prefetch (issued before MFMA phase)
  }
#undef GSTAGE

  if (MODE == 1) {
#pragma unroll
    for (int mt = 0; mt < MT; ++mt)
#pragma unroll
      for (int nt = 0; nt < NT; ++nt)
#pragma unroll
        for (int r = 0; r < 4; ++r) {
          int m = m0 + wr * (BM / 2) + mt * 16 + lg * 4 + r;
          int n = n0 + wc * (BN / 2) + nt * 16 + lm;
          Cout[(size_t)m * 1024 + n] = acc[mt][nt][r];
        }
    return;
  }

  // MODE 0 epilogue (BM=64, BN=128): region by n0; one head per wave-column.
  const int region = n0 >> 10;  // 0=Q 1=K 2=V
  const int b = m0 >> 10, s0 = m0 & 1023;
  if (region < 2) {
    u16* dst = region == 0 ? Qo : Ko;
    const float scl = region == 0 ? 0.125f * LOG2E : 1.f;  // Q in log2 domain
#pragma unroll
    for (int mt = 0; mt < MT; ++mt)
#pragma unroll
      for (int nt = 0; nt < NT; ++nt)
#pragma unroll
        for (int r = 0; r < 4; ++r) {
          int m = m0 + wr * (BM / 2) + mt * 16 + lg * 4 + r;
          int n = n0 + wc * (BN / 2) + nt * 16 + lm;
          int e = n & 1023, h = e >> 6, d = e & 63;
          dst[(size_t)(((b << 4) + h) * 1024 + (m & 1023)) * 64 + d] =
              f2bf(acc[mt][nt][r] * scl);
        }
    if (region == 1) {
      // egk = exp(-1.4*min(sum_d K^2/64, 2)); wave-column wc = one head
      int hh = ((n0 - 1024) >> 6) + wc;
#pragma unroll
      for (int mt = 0; mt < MT; ++mt)
#pragma unroll
        for (int r = 0; r < 4; ++r) {
          float ss = 0.f;
#pragma unroll
          for (int nt = 0; nt < NT; ++nt) ss += acc[mt][nt][r] * acc[mt][nt][r];
          ss += __shfl_xor(ss, 1);
          ss += __shfl_xor(ss, 2);
          ss += __shfl_xor(ss, 4);
          ss += __shfl_xor(ss, 8);
          if (lm == 0) {
            int s = s0 + wr * (BM / 2) + mt * 16 + lg * 4 + r;
            float g = 1.4f * fminf(ss * (1.f / 64.f), 2.f);
            egk_out[(size_t)(((b << 4) + hh)) * 1024 + s] = __expf(-g);
          }
        }
    }
  } else {
    // V: transpose via LDS, tile[64 d][64 m] swizzled; one head per wc half
    u16* tile = SM[0];
#pragma unroll
    for (int half = 0; half < 2; ++half) {
      if (wc == half) {
#pragma unroll
        for (int mt = 0; mt < MT; ++mt)
#pragma unroll
          for (int nt = 0; nt < NT; ++nt)
#pragma unroll
            for (int r = 0; r < 4; ++r) {
              int d = nt * 16 + lm;
              int mloc = wr * (BM / 2) + mt * 16 + lg * 4 + r;
              tile[d * 64 + (mloc ^ ((d & 7) << 3))] = f2bf(acc[mt][nt][r]);
            }
      }
      __syncthreads();
      int hh = ((n0 - 2048) >> 6) + half;
#pragma unroll
      for (int j = 0; j < 2; ++j) {
        int dd = (t >> 3) + 32 * j, mc = t & 7;
        u16x8 v = *(const u16x8*)&tile[dd * 64 + ((mc * 8) ^ ((dd & 7) << 3))];
        *(u16x8*)(Vt + ((size_t)(((b << 4) + hh) * 64 + dd)) * 1024 + s0 + mc * 8) = v;
      }
      __syncthreads();
    }
  }
}

// ---------------- fused gated flash attention + entropy (log2 domain) --------
// grid 512 (XCD-swizzled); 4 waves/block, 16 q-rows/wave, KVBLK=128, dbuf LDS.
// Scores arrive already scaled by log2e (Q pre-scale); p = exp2(sh2);
// W accumulated in log2 units, converted by ln2 once in the epilogue.
__global__ __launch_bounds__(256, 2) void k_attn(const u16* __restrict__ Q,
                                                 const u16* __restrict__ Kt,
                                                 const u16* __restrict__ Vt,
                                                 const float* __restrict__ efq,
                                                 const float* __restrict__ egk,
                                                 u16* __restrict__ Ob,
                                                 float* __restrict__ Sst) {
  __shared__ __align__(16) u16 Ks[2][128 * 64];  // [k][d], swizzled (16KB ea)
  __shared__ __align__(16) u16 Vs[2][64 * 128];  // [d][k], swizzled (16KB ea)
  __shared__ __align__(16) u32 Ps[4][16][64];    // per-wave P pairs (16KB)
  const int i = blockIdx.x;
  const int lb = ((i & 7) << 6) | (i >> 3);  // XCD-bijective: 4 bh per XCD
  const int bh = lb >> 4, qblk = lb & 15;
  const int t = threadIdx.x, lane = t & 63, w = t >> 6;
  const int lm = lane & 15, lg = lane >> 4;
  const int b = bh >> 4, h = bh & 15;
  const size_t bhS = (size_t)bh << 10;
  const int qb = qblk * 64 + w * 16;

#define STAGE(buf, k0)                                                         \
  {                                                                            \
    int rowK = t >> 3, cK = t & 7;                                             \
    int rowV = t >> 4, cV = t & 15;                                            \
    _Pragma("unroll") for (int i2 = 0; i2 < 4; ++i2) {                         \
      int rr = rowK + 32 * i2;                                                 \
      gload_lds16(Kt + (bhS + (k0) + rr) * 64 + ((cK ^ (rr & 7)) * 8),         \
                  (char*)Ks[buf] + t * 16 + i2 * 4096);                        \
      int dd2 = rowV + 16 * i2;                                                \
      gload_lds16(Vt + ((size_t)bh * 64 + dd2) * 1024 + (k0) +                 \
                      ((cV ^ (dd2 & 15)) * 8),                                 \
                  (char*)Vs[buf] + t * 16 + i2 * 4096);                        \
    }                                                                          \
  }

  bf16x8 qf[2];
#pragma unroll
  for (int ks = 0; ks < 2; ++ks)
    qf[ks] = *(const bf16x8*)(Q + (bhS + qb + lm) * 64 + ks * 32 + lg * 8);
  const float efql = efq[bhS + qb + lm];  // = log2e * exp(-f(q))

  f32x4 Oacc[4] = {};
  float m_r = -1e30f, l_r = 0.f, W_r = 0.f;  // m,W in log2 units

  STAGE(0, 0);
  f32x4 egN[8];
#pragma unroll
  for (int nt = 0; nt < 8; ++nt)
    egN[nt] = *(const f32x4*)&egk[bhS + nt * 16 + lg * 4];
  __syncthreads();

  for (int kt = 0; kt < 8; ++kt) {
    const int cur = kt & 1;
    if (kt < 7) STAGE(cur ^ 1, (kt + 1) * 128);

    // swapped QK^T: lane owns q = lm; k = nt*16 + lg*4 + r (log2-scaled scores)
    f32x4 c_[8];
#pragma unroll
    for (int nt = 0; nt < 8; ++nt) {
      c_[nt] = (f32x4){0.f, 0.f, 0.f, 0.f};
#pragma unroll
      for (int ks = 0; ks < 2; ++ks) {
        int row = nt * 16 + lm;
        int byo = (((ks * 4 + lg) ^ (row & 7)) << 4);
        bf16x8 kb = *(const bf16x8*)((const char*)Ks[cur] + row * 128 + byo);
        c_[nt] = MFMA16(kb, qf[ks], c_[nt]);
      }
    }

    // gate in log2: lsig2 = -log2(1+x), series in y = log2e*x (= efql*egk)
    float v_[8][4];
    float lmax = -3e38f;
#pragma unroll
    for (int nt = 0; nt < 8; ++nt) {
      f32x4 eg = egN[nt];
#pragma unroll
      for (int r = 0; r < 4; ++r) {
        float y = efql * eg[r];
        float lsig = -y * (1.f - y * (0.34657359f -
                     y * (0.16015698f - y * (0.08327429f - 0.04616624f * y))));
        float vv = c_[nt][r] + lsig;
        v_[nt][r] = vv;
        lmax = fmaxf(lmax, vv);
      }
    }
    if (kt < 7) {
#pragma unroll
      for (int nt = 0; nt < 8; ++nt)
        egN[nt] = *(const f32x4*)&egk[bhS + (kt + 1) * 128 + nt * 16 + lg * 4];
    }
    lmax = fmaxf(lmax, __shfl_xor(lmax, 16));
    lmax = fmaxf(lmax, __shfl_xor(lmax, 32));

    // defer-max (T13): threshold 5 natural units = 5*log2e in log2 units
    if (__any(lmax > m_r + 7.2134752f)) {
      float mn = fmaxf(m_r, lmax);
      float dd = m_r - mn;
      float sc = exp2fast(dd);
      W_r = sc * (W_r + dd * l_r);
      l_r *= sc;
      m_r = mn;
      float scO[4];
#pragma unroll
      for (int r = 0; r < 4; ++r) scO[r] = __shfl(sc, (lane & 48) | (lg * 4 + r));
#pragma unroll
      for (int dt = 0; dt < 4; ++dt)
#pragma unroll
        for (int r = 0; r < 4; ++r) Oacc[dt][r] *= scO[r];
    }

    // p = exp2(v-m); accumulate l, W2; pack to bf16 pairs
    float psum = 0.f, wsum = 0.f;
    u32 pw[16];
#pragma unroll
    for (int nt = 0; nt < 8; ++nt) {
      float p_[4];
#pragma unroll
      for (int r = 0; r < 4; ++r) {
        float sh = v_[nt][r] - m_r;
        float p = exp2fast(sh);
        p_[r] = p;
        psum += p;
        wsum = fmaf(p, sh, wsum);
      }
      asm("v_cvt_pk_bf16_f32 %0, %1, %2" : "=v"(pw[nt * 2 + 0]) : "v"(p_[0]), "v"(p_[1]));
      asm("v_cvt_pk_bf16_f32 %0, %1, %2" : "=v"(pw[nt * 2 + 1]) : "v"(p_[2]), "v"(p_[3]));
    }
    psum += __shfl_xor(psum, 16);
    psum += __shfl_xor(psum, 32);
    wsum += __shfl_xor(wsum, 16);
    wsum += __shfl_xor(wsum, 32);
    l_r += psum;
    W_r += wsum;

    // P -> per-wave LDS (swizzled u32 pairs)
    u32* prow = &Ps[w][lm][0];
    const int sw = (lm & 7) << 2;
#pragma unroll
    for (int nt = 0; nt < 8; ++nt) {
      int idx = (nt * 8 + lg * 2) ^ sw;
      uint2 pr;
      pr.x = pw[nt * 2 + 0];
      pr.y = pw[nt * 2 + 1];
      *(uint2*)(prow + idx) = pr;
    }

    bf16x8 pa[4];
#pragma unroll
    for (int ks = 0; ks < 4; ++ks) {
      int idx = (ks * 16 + lg * 4) ^ sw;
      pa[ks] = *(const bf16x8*)(prow + idx);
    }
#pragma unroll
    for (int dt = 0; dt < 4; ++dt) {
#pragma unroll
      for (int ks = 0; ks < 4; ++ks) {
        int row = dt * 16 + lm;
        int byo = (((ks * 4 + lg) ^ (row & 15)) << 4);
        bf16x8 vb = *(const bf16x8*)((const char*)Vs[cur] + row * 256 + byo);
        Oacc[dt] = MFMA16(pa[ks], vb, Oacc[dt]);
      }
    }
    __syncthreads();  // drains vmcnt(0): next buffer staged & ready
  }

  float invl = 1.f / l_r;
  float entv = __logf(l_r) - (W_r * LN2) * invl;  // W back to natural units
  float invO[4];
#pragma unroll
  for (int r = 0; r < 4; ++r) invO[r] = __shfl(invl, (lane & 48) | (lg * 4 + r));
#pragma unroll
  for (int dt = 0; dt < 4; ++dt)
#pragma unroll
    for (int r = 0; r < 4; ++r) {
      int srow = qb + lg * 4 + r;
      int col = h * 64 + dt * 16 + lm;
      Ob[(size_t)(b * 1024 + srow) * 1024 + col] = f2bf(Oacc[dt][r] * invO[r]);
    }
  if (lg == 0) Sst[bhS + qb + lm] = entv;
#undef STAGE
}

// ---------------- workspace layout (bytes) ----------------
static constexpr size_t OFF_XB = 0;                    // 4 MB  x bf16
static constexpr size_t OFF_WB = 4ull << 20;           // 6 MB  Wq|Wk|Wv bf16
static constexpr size_t OFF_Q = 10ull << 20;           // 4 MB  Q bf16, pre-scaled
static constexpr size_t OFF_K = 14ull << 20;           // 4 MB  K bf16
static constexpr size_t OFF_OB = 18ull << 20;          // 4 MB  attn out bf16
static constexpr size_t OFF_VT = 22ull << 20;          // 4 MB  V^T bf16 (B,H,64,S)
static constexpr size_t OFF_WOB = 26ull << 20;         // 2 MB  Wo bf16
static constexpr size_t OFF_FQ = 28ull << 20;          // 128 KB f32 log2e*exp(-fq)
static constexpr size_t OFF_GK = (28ull << 20) + (128ull << 10);  // 128 KB f32 exp(-gk)

extern "C" void kernel_launch(void* const* d_in, const int* in_sizes, int n_in,
                              void* d_out, int out_size, void* d_ws, size_t ws_size,
                              hipStream_t stream) {
  const float* x = (const float*)d_in[0];
  const float* ent = (const float*)d_in[1];
  const float* Wq = (const float*)d_in[2];
  const float* Wk = (const float*)d_in[3];
  const float* Wv = (const float*)d_in[4];
  const float* Wo = (const float*)d_in[5];
  (void)in_sizes; (void)n_in; (void)out_size; (void)ws_size;

  char* ws = (char*)d_ws;
  u16* xb = (u16*)(ws + OFF_XB);
  u16* Wb = (u16*)(ws + OFF_WB);
  u16* Qb = (u16*)(ws + OFF_Q);
  u16* Kb = (u16*)(ws + OFF_K);
  u16* Ob = (u16*)(ws + OFF_OB);
  u16* Vtb = (u16*)(ws + OFF_VT);
  u16* Wob = (u16*)(ws + OFF_WOB);
  float* efqd = (float*)(ws + OFF_FQ);
  float* egkd = (float*)(ws + OFF_GK);
  float* outp = (float*)d_out;
  float* Sst = outp + 2u * 1024u * 1024u;

  k_prep<<<3200, 256, 0, stream>>>(x, Wq, Wk, Wv, Wo, ent, xb, Wb, Wob, efqd);

  k_gemm<64, 128, 3072, 0><<<768, 256, 0, stream>>>(xb, Wb, 1024, Qb, Kb, Vtb,
                                                    egkd, nullptr);

  k_attn<<<512, 256, 0, stream>>>(Qb, Kb, Vtb, efqd, egkd, Ob, Sst);

  k_gemm<64, 64, 1024, 1><<<512, 256, 0, stream>>>(Ob, Wob, 1024, nullptr, nullptr,
                                                   nullptr, nullptr, outp);
}

// Round 6
// 67.547 us; speedup vs baseline: 2.1716x; 1.0068x over previous
//
#include <hip/hip_runtime.h>
#include <cstdint>

#define DEVINL __device__ __forceinline__

typedef __attribute__((ext_vector_type(8))) short bf16x8;
typedef __attribute__((ext_vector_type(4))) float f32x4;
typedef __attribute__((ext_vector_type(8))) unsigned short u16x8;
typedef unsigned short u16;
typedef unsigned int u32;

#define MFMA16(a, b, c) __builtin_amdgcn_mfma_f32_16x16x32_bf16(a, b, c, 0, 0, 0)

// log2-domain constants
#define LOG2E 1.4426950408889634f
#define LN2 0.69314718055994531f

DEVINL u16 f2bf(float x) {
  u32 u = __builtin_bit_cast(u32, x);
  u += 0x7FFFu + ((u >> 16) & 1u);
  return (u16)(u >> 16);
}
DEVINL float bf2f(u16 s) {
  u32 u = ((u32)s) << 16;
  return __builtin_bit_cast(float, u);
}
DEVINL float exp2fast(float x) {  // v_exp_f32 IS 2^x
  float r;
  asm("v_exp_f32 %0, %1" : "=v"(r) : "v"(x));
  return r;
}
DEVINL void gload_lds16(const void* g, void* l) {
  __builtin_amdgcn_global_load_lds(
      (const __attribute__((address_space(1))) unsigned int*)g,
      (__attribute__((address_space(3))) unsigned int*)l, 16, 0, 0);
}

// ---------------- fused prologue: f32->bf16 converts + efq ------------------
__global__ __launch_bounds__(256) void k_prep(const float* __restrict__ x,
                                              const float* __restrict__ Wq,
                                              const float* __restrict__ Wk,
                                              const float* __restrict__ Wv,
                                              const float* __restrict__ Wo,
                                              const float* __restrict__ ent,
                                              u16* __restrict__ xb,
                                              u16* __restrict__ Wb,
                                              u16* __restrict__ Wob,
                                              float* __restrict__ efq) {
  const int bid = blockIdx.x;
  if (bid < 3072) {
    const float* src;
    u16* dst;
    int base;
    if (bid < 1024)      { src = x;  dst = xb;            base = bid; }
    else if (bid < 1536) { src = Wq; dst = Wb;            base = bid - 1024; }
    else if (bid < 2048) { src = Wk; dst = Wb + (1u<<20); base = bid - 1536; }
    else if (bid < 2560) { src = Wv; dst = Wb + (2u<<20); base = bid - 2048; }
    else                 { src = Wo; dst = Wob;           base = bid - 2560; }
    int i = base * 256 + threadIdx.x;
    const float4* s4 = (const float4*)src;
    float4 a = s4[2 * i], b = s4[2 * i + 1];
    u16x8 o;
    o[0] = f2bf(a.x); o[1] = f2bf(a.y); o[2] = f2bf(a.z); o[3] = f2bf(a.w);
    o[4] = f2bf(b.x); o[5] = f2bf(b.y); o[6] = f2bf(b.z); o[7] = f2bf(b.w);
    *(u16x8*)(dst + 8 * i) = o;
  } else {
    int i = (bid - 3072) * 256 + threadIdx.x;
    float e = ent[i];
    float Et = 1.f / (1.f + __expf(-5.f * (e - 0.3f)));
    // natural-scale: efq = exp(-f(q)); gate uses x = efq*egk, lsig2 = -log2(1+x)
    efq[i] = __expf(-(5.f * Et - 0.3f * e));
  }
}

// ---------------- tiled bf16 GEMM, C = A * B^T, BK=64, dbuf LDS, 2-phase -----
// 1D grid, XCD-bijective swizzle. M fixed = 2048.
// MODE 0 (BM=64,BN=128): QKV epilogues (Q*0.125*log2e -> Qo; K -> Ko + egk; V -> Vt).
// MODE 1: f32 store to Cout (N=1024).
template <int BM, int BN, int NDIM, int MODE>
__global__ __launch_bounds__(256) void k_gemm(const u16* __restrict__ A,
                                              const u16* __restrict__ Bw,
                                              int Kdim, u16* __restrict__ Qo,
                                              u16* __restrict__ Ko,
                                              u16* __restrict__ Vt,
                                              float* __restrict__ egk_out,
                                              float* __restrict__ Cout) {
  constexpr int MT = BM / 32, NT = BN / 32;
  constexpr int MB = 2048 / BM, NB = NDIM / BN;
  constexpr int CPX = MB * NB / 8;
  __shared__ __align__(16) u16 SM[2][(BM + BN) * 64];
  const int t = threadIdx.x;
  const int lb = (blockIdx.x & 7) * CPX + (blockIdx.x >> 3);
  const int m0 = (lb % MB) * BM, n0 = (lb / MB) * BN;
  const int lane = t & 63, w = t >> 6;
  const int wr = w >> 1, wc = w & 1, lm = lane & 15, lg = lane >> 4;
  const int rs = t >> 3, cs = t & 7;
  f32x4 acc[MT][NT] = {};

#define GSTAGE(buf, kt)                                                        \
  {                                                                            \
    u16* As_ = SM[buf];                                                        \
    u16* Bs_ = SM[buf] + BM * 64;                                              \
    _Pragma("unroll") for (int i = 0; i < BM / 32; ++i) {                      \
      int rr = rs + 32 * i;                                                    \
      gload_lds16(A + (size_t)(m0 + rr) * Kdim + (kt) + ((cs ^ (rr & 7)) * 8), \
                  (char*)As_ + t * 16 + i * 4096);                             \
    }                                                                          \
    _Pragma("unroll") for (int i = 0; i < BN / 32; ++i) {                      \
      int rr = rs + 32 * i;                                                    \
      gload_lds16(Bw + (size_t)(n0 + rr) * Kdim + (kt) + ((cs ^ (rr & 7)) * 8),\
                  (char*)Bs_ + t * 16 + i * 4096);                             \
    }                                                                          \
  }

  GSTAGE(0, 0);
  __syncthreads();
  const int nk = Kdim >> 6;
  for (int ki = 0; ki < nk; ++ki) {
    const int cur = ki & 1;
    if (ki + 1 < nk) GSTAGE(cur ^ 1, (ki + 1) * 64);
    const u16* As = SM[cur];
    const u16* Bs = SM[cur] + BM * 64;
#pragma unroll
    for (int ks = 0; ks < 2; ++ks) {
      bf16x8 af[MT], bf[NT];
#pragma unroll
      for (int mt = 0; mt < MT; ++mt) {
        int row = wr * (BM / 2) + mt * 16 + lm;
        af[mt] = *(const bf16x8*)((const char*)As + row * 128 +
                                  (((ks * 4 + lg) ^ (row & 7)) << 4));
      }
#pragma unroll
      for (int nt = 0; nt < NT; ++nt) {
        int row = wc * (BN / 2) + nt * 16 + lm;
        bf[nt] = *(const bf16x8*)((const char*)Bs + row * 128 +
                                  (((ks * 4 + lg) ^ (row & 7)) << 4));
      }
#pragma unroll
      for (int mt = 0; mt < MT; ++mt)
#pragma unroll
        for (int nt = 0; nt < NT; ++nt)
          acc[mt][nt] = MFMA16(af[mt], bf[nt], acc[mt][nt]);
    }
    __syncthreads();  // drains this iter's prefetch (issued before MFMA phase)
  }
#undef GSTAGE

  if (MODE == 1) {
#pragma unroll
    for (int mt = 0; mt < MT; ++mt)
#pragma unroll
      for (int nt = 0; nt < NT; ++nt)
#pragma unroll
        for (int r = 0; r < 4; ++r) {
          int m = m0 + wr * (BM / 2) + mt * 16 + lg * 4 + r;
          int n = n0 + wc * (BN / 2) + nt * 16 + lm;
          Cout[(size_t)m * 1024 + n] = acc[mt][nt][r];
        }
    return;
  }

  // MODE 0 epilogue (BM=64, BN=128): region by n0; one head per wave-column.
  const int region = n0 >> 10;  // 0=Q 1=K 2=V
  const int b = m0 >> 10, s0 = m0 & 1023;
  if (region < 2) {
    u16* dst = region == 0 ? Qo : Ko;
    const float scl = region == 0 ? 0.125f * LOG2E : 1.f;  // Q in log2 domain
#pragma unroll
    for (int mt = 0; mt < MT; ++mt)
#pragma unroll
      for (int nt = 0; nt < NT; ++nt)
#pragma unroll
        for (int r = 0; r < 4; ++r) {
          int m = m0 + wr * (BM / 2) + mt * 16 + lg * 4 + r;
          int n = n0 + wc * (BN / 2) + nt * 16 + lm;
          int e = n & 1023, h = e >> 6, d = e & 63;
          dst[(size_t)(((b << 4) + h) * 1024 + (m & 1023)) * 64 + d] =
              f2bf(acc[mt][nt][r] * scl);
        }
    if (region == 1) {
      // egk = exp(-1.4*min(sum_d K^2/64, 2)); wave-column wc = one head
      int hh = ((n0 - 1024) >> 6) + wc;
#pragma unroll
      for (int mt = 0; mt < MT; ++mt)
#pragma unroll
        for (int r = 0; r < 4; ++r) {
          float ss = 0.f;
#pragma unroll
          for (int nt = 0; nt < NT; ++nt) ss += acc[mt][nt][r] * acc[mt][nt][r];
          ss += __shfl_xor(ss, 1);
          ss += __shfl_xor(ss, 2);
          ss += __shfl_xor(ss, 4);
          ss += __shfl_xor(ss, 8);
          if (lm == 0) {
            int s = s0 + wr * (BM / 2) + mt * 16 + lg * 4 + r;
            float g = 1.4f * fminf(ss * (1.f / 64.f), 2.f);
            egk_out[(size_t)(((b << 4) + hh)) * 1024 + s] = __expf(-g);
          }
        }
    }
  } else {
    // V: transpose via LDS, tile[64 d][64 m] swizzled; one head per wc half
    u16* tile = SM[0];
#pragma unroll
    for (int half = 0; half < 2; ++half) {
      if (wc == half) {
#pragma unroll
        for (int mt = 0; mt < MT; ++mt)
#pragma unroll
          for (int nt = 0; nt < NT; ++nt)
#pragma unroll
            for (int r = 0; r < 4; ++r) {
              int d = nt * 16 + lm;
              int mloc = wr * (BM / 2) + mt * 16 + lg * 4 + r;
              tile[d * 64 + (mloc ^ ((d & 7) << 3))] = f2bf(acc[mt][nt][r]);
            }
      }
      __syncthreads();
      int hh = ((n0 - 2048) >> 6) + half;
#pragma unroll
      for (int j = 0; j < 2; ++j) {
        int dd = (t >> 3) + 32 * j, mc = t & 7;
        u16x8 v = *(const u16x8*)&tile[dd * 64 + ((mc * 8) ^ ((dd & 7) << 3))];
        *(u16x8*)(Vt + ((size_t)(((b << 4) + hh) * 64 + dd)) * 1024 + s0 + mc * 8) = v;
      }
      __syncthreads();
    }
  }
}

// ---------------- fused gated flash attention + entropy (log2 domain) --------
// grid 512 (XCD-swizzled); 4 waves/block, 16 q-rows/wave, KVBLK=128, dbuf LDS.
// Gate via hardware v_log_f32: v = c - log2(1+x), x = efq*egk (natural).
__global__ __launch_bounds__(256, 2) void k_attn(const u16* __restrict__ Q,
                                                 const u16* __restrict__ Kt,
                                                 const u16* __restrict__ Vt,
                                                 const float* __restrict__ efq,
                                                 const float* __restrict__ egk,
                                                 u16* __restrict__ Ob,
                                                 float* __restrict__ Sst) {
  __shared__ __align__(16) u16 Ks[2][128 * 64];  // [k][d], swizzled (16KB ea)
  __shared__ __align__(16) u16 Vs[2][64 * 128];  // [d][k], swizzled (16KB ea)
  __shared__ __align__(16) u32 Ps[4][16][64];    // per-wave P pairs (16KB)
  const int i = blockIdx.x;
  const int lb = ((i & 7) << 6) | (i >> 3);  // XCD-bijective: 4 bh per XCD
  const int bh = lb >> 4, qblk = lb & 15;
  const int t = threadIdx.x, lane = t & 63, w = t >> 6;
  const int lm = lane & 15, lg = lane >> 4;
  const int b = bh >> 4, h = bh & 15;
  const size_t bhS = (size_t)bh << 10;
  const int qb = qblk * 64 + w * 16;

#define STAGE(buf, k0)                                                         \
  {                                                                            \
    int rowK = t >> 3, cK = t & 7;                                             \
    int rowV = t >> 4, cV = t & 15;                                            \
    _Pragma("unroll") for (int i2 = 0; i2 < 4; ++i2) {                         \
      int rr = rowK + 32 * i2;                                                 \
      gload_lds16(Kt + (bhS + (k0) + rr) * 64 + ((cK ^ (rr & 7)) * 8),         \
                  (char*)Ks[buf] + t * 16 + i2 * 4096);                        \
      int dd2 = rowV + 16 * i2;                                                \
      gload_lds16(Vt + ((size_t)bh * 64 + dd2) * 1024 + (k0) +                 \
                      ((cV ^ (dd2 & 15)) * 8),                                 \
                  (char*)Vs[buf] + t * 16 + i2 * 4096);                        \
    }                                                                          \
  }

  bf16x8 qf[2];
#pragma unroll
  for (int ks = 0; ks < 2; ++ks)
    qf[ks] = *(const bf16x8*)(Q + (bhS + qb + lm) * 64 + ks * 32 + lg * 8);
  const float efql = efq[bhS + qb + lm];  // = exp(-f(q)), natural scale

  f32x4 Oacc[4] = {};
  float m_r = -1e30f, l_r = 0.f, W_r = 0.f;  // m,W in log2 units

  STAGE(0, 0);
  f32x4 egN[8];
#pragma unroll
  for (int nt = 0; nt < 8; ++nt)
    egN[nt] = *(const f32x4*)&egk[bhS + nt * 16 + lg * 4];
  __syncthreads();

  for (int kt = 0; kt < 8; ++kt) {
    const int cur = kt & 1;
    if (kt < 7) STAGE(cur ^ 1, (kt + 1) * 128);

    // swapped QK^T: lane owns q = lm; k = nt*16 + lg*4 + r (log2-scaled scores)
    f32x4 c_[8];
    __builtin_amdgcn_s_setprio(1);
#pragma unroll
    for (int nt = 0; nt < 8; ++nt) {
      c_[nt] = (f32x4){0.f, 0.f, 0.f, 0.f};
#pragma unroll
      for (int ks = 0; ks < 2; ++ks) {
        int row = nt * 16 + lm;
        int byo = (((ks * 4 + lg) ^ (row & 7)) << 4);
        bf16x8 kb = *(const bf16x8*)((const char*)Ks[cur] + row * 128 + byo);
        c_[nt] = MFMA16(kb, qf[ks], c_[nt]);
      }
    }
    __builtin_amdgcn_s_setprio(0);

    // gate: v = c - log2(1+x), x = efq*egk  (hardware v_log_f32, exact)
    float v_[8][4];
    float lmax = -3e38f;
#pragma unroll
    for (int nt = 0; nt < 8; ++nt) {
      f32x4 eg = egN[nt];
#pragma unroll
      for (int r = 0; r < 4; ++r) {
        float xg = efql * eg[r];
        v_[nt][r] = c_[nt][r] - __log2f(1.f + xg);
      }
      // v_max3-friendly reduction tree
      lmax = fmaxf(fmaxf(lmax, v_[nt][0]),
                   fmaxf(fmaxf(v_[nt][1], v_[nt][2]), v_[nt][3]));
    }
    if (kt < 7) {
#pragma unroll
      for (int nt = 0; nt < 8; ++nt)
        egN[nt] = *(const f32x4*)&egk[bhS + (kt + 1) * 128 + nt * 16 + lg * 4];
    }
    lmax = fmaxf(lmax, __shfl_xor(lmax, 16));
    lmax = fmaxf(lmax, __shfl_xor(lmax, 32));

    // defer-max (T13): threshold 5 natural units = 5*log2e in log2 units
    if (__any(lmax > m_r + 7.2134752f)) {
      float mn = fmaxf(m_r, lmax);
      float dd = m_r - mn;
      float sc = exp2fast(dd);
      W_r = sc * (W_r + dd * l_r);
      l_r *= sc;
      m_r = mn;
      float scO[4];
#pragma unroll
      for (int r = 0; r < 4; ++r) scO[r] = __shfl(sc, (lane & 48) | (lg * 4 + r));
#pragma unroll
      for (int dt = 0; dt < 4; ++dt)
#pragma unroll
        for (int r = 0; r < 4; ++r) Oacc[dt][r] *= scO[r];
    }

    // p = exp2(v-m); accumulate l, W2; pack to bf16 pairs
    float psum = 0.f, wsum = 0.f;
    u32 pw[16];
#pragma unroll
    for (int nt = 0; nt < 8; ++nt) {
      float p_[4];
#pragma unroll
      for (int r = 0; r < 4; ++r) {
        float sh = v_[nt][r] - m_r;
        float p = exp2fast(sh);
        p_[r] = p;
        psum += p;
        wsum = fmaf(p, sh, wsum);
      }
      asm("v_cvt_pk_bf16_f32 %0, %1, %2" : "=v"(pw[nt * 2 + 0]) : "v"(p_[0]), "v"(p_[1]));
      asm("v_cvt_pk_bf16_f32 %0, %1, %2" : "=v"(pw[nt * 2 + 1]) : "v"(p_[2]), "v"(p_[3]));
    }
    psum += __shfl_xor(psum, 16);
    psum += __shfl_xor(psum, 32);
    wsum += __shfl_xor(wsum, 16);
    wsum += __shfl_xor(wsum, 32);
    l_r += psum;
    W_r += wsum;

    // P -> per-wave LDS (swizzled u32 pairs)
    u32* prow = &Ps[w][lm][0];
    const int sw = (lm & 7) << 2;
#pragma unroll
    for (int nt = 0; nt < 8; ++nt) {
      int idx = (nt * 8 + lg * 2) ^ sw;
      uint2 pr;
      pr.x = pw[nt * 2 + 0];
      pr.y = pw[nt * 2 + 1];
      *(uint2*)(prow + idx) = pr;
    }

    bf16x8 pa[4];
#pragma unroll
    for (int ks = 0; ks < 4; ++ks) {
      int idx = (ks * 16 + lg * 4) ^ sw;
      pa[ks] = *(const bf16x8*)(prow + idx);
    }
    __builtin_amdgcn_s_setprio(1);
#pragma unroll
    for (int dt = 0; dt < 4; ++dt) {
#pragma unroll
      for (int ks = 0; ks < 4; ++ks) {
        int row = dt * 16 + lm;
        int byo = (((ks * 4 + lg) ^ (row & 15)) << 4);
        bf16x8 vb = *(const bf16x8*)((const char*)Vs[cur] + row * 256 + byo);
        Oacc[dt] = MFMA16(pa[ks], vb, Oacc[dt]);
      }
    }
    __builtin_amdgcn_s_setprio(0);
    __syncthreads();  // drains vmcnt(0): next buffer staged & ready
  }

  float invl = 1.f / l_r;
  float entv = __logf(l_r) - (W_r * LN2) * invl;  // W back to natural units
  float invO[4];
#pragma unroll
  for (int r = 0; r < 4; ++r) invO[r] = __shfl(invl, (lane & 48) | (lg * 4 + r));
#pragma unroll
  for (int dt = 0; dt < 4; ++dt)
#pragma unroll
    for (int r = 0; r < 4; ++r) {
      int srow = qb + lg * 4 + r;
      int col = h * 64 + dt * 16 + lm;
      Ob[(size_t)(b * 1024 + srow) * 1024 + col] = f2bf(Oacc[dt][r] * invO[r]);
    }
  if (lg == 0) Sst[bhS + qb + lm] = entv;
#undef STAGE
}

// ---------------- workspace layout (bytes) ----------------
static constexpr size_t OFF_XB = 0;                    // 4 MB  x bf16
static constexpr size_t OFF_WB = 4ull << 20;           // 6 MB  Wq|Wk|Wv bf16
static constexpr size_t OFF_Q = 10ull << 20;           // 4 MB  Q bf16, pre-scaled
static constexpr size_t OFF_K = 14ull << 20;           // 4 MB  K bf16
static constexpr size_t OFF_OB = 18ull << 20;          // 4 MB  attn out bf16
static constexpr size_t OFF_VT = 22ull << 20;          // 4 MB  V^T bf16 (B,H,64,S)
static constexpr size_t OFF_WOB = 26ull << 20;         // 2 MB  Wo bf16
static constexpr size_t OFF_FQ = 28ull << 20;          // 128 KB f32 exp(-fq)
static constexpr size_t OFF_GK = (28ull << 20) + (128ull << 10);  // 128 KB f32 exp(-gk)

extern "C" void kernel_launch(void* const* d_in, const int* in_sizes, int n_in,
                              void* d_out, int out_size, void* d_ws, size_t ws_size,
                              hipStream_t stream) {
  const float* x = (const float*)d_in[0];
  const float* ent = (const float*)d_in[1];
  const float* Wq = (const float*)d_in[2];
  const float* Wk = (const float*)d_in[3];
  const float* Wv = (const float*)d_in[4];
  const float* Wo = (const float*)d_in[5];
  (void)in_sizes; (void)n_in; (void)out_size; (void)ws_size;

  char* ws = (char*)d_ws;
  u16* xb = (u16*)(ws + OFF_XB);
  u16* Wb = (u16*)(ws + OFF_WB);
  u16* Qb = (u16*)(ws + OFF_Q);
  u16* Kb = (u16*)(ws + OFF_K);
  u16* Ob = (u16*)(ws + OFF_OB);
  u16* Vtb = (u16*)(ws + OFF_VT);
  u16* Wob = (u16*)(ws + OFF_WOB);
  float* efqd = (float*)(ws + OFF_FQ);
  float* egkd = (float*)(ws + OFF_GK);
  float* outp = (float*)d_out;
  float* Sst = outp + 2u * 1024u * 1024u;

  k_prep<<<3200, 256, 0, stream>>>(x, Wq, Wk, Wv, Wo, ent, xb, Wb, Wob, efqd);

  k_gemm<64, 128, 3072, 0><<<768, 256, 0, stream>>>(xb, Wb, 1024, Qb, Kb, Vtb,
                                                    egkd, nullptr);

  k_attn<<<512, 256, 0, stream>>>(Qb, Kb, Vtb, efqd, egkd, Ob, Sst);

  k_gemm<64, 64, 1024, 1><<<512, 256, 0, stream>>>(Ob, Wob, 1024, nullptr, nullptr,
                                                   nullptr, nullptr, outp);
}